// Round 5
// baseline (923.978 us; speedup 1.0000x reference)
//
#include <hip/hip_runtime.h>
#include <math.h>
#include <stddef.h>

// ---------------------------------------------------------------------------
// BiDiGemma forward. Round 14: R13 +
//  (1) dual-up MLP GEMM widened to BN=128 (grid 6x256): 2x MFMA per barrier,
//      half the A re-reads, half the per-output staging overhead.
//  (2) rms_h_k (hi-plane-only) for rn0_t / rn0_c / rn1_c sites whose lo plane
//      was never read (consumers are TERMS<=2 = A-hi-only). -50 MB dead stores.
// ---------------------------------------------------------------------------

#define BB   4
#define SS   4096
#define DD   256
#define HH   4
#define HDIM 64
#define EE   768
#define RR   (BB*SS)        // rows per branch
#define RR2  (2*RR)         // merged rows
#define WNN  256
#define CH   64
#define NCH  (SS/CH)

typedef __attribute__((ext_vector_type(8))) short bfrag;
typedef __attribute__((ext_vector_type(4))) float f4acc;

__device__ __forceinline__ float geluf(float x){
  float u = 1.5957691216f*(x + 0.044715f*x*x*x);
  float e = __expf(u);
  float t = 1.f - 2.f/(e+1.f);
  return 0.5f*x*(1.f+t);
}
__device__ __forceinline__ float sigm(float x){ return 1.0f/(1.0f+expf(-x)); }

__device__ __forceinline__ unsigned short f2bf(float x){
  unsigned u = __float_as_uint(x);
  return (unsigned short)((u + 0x7FFFu + ((u>>16)&1u)) >> 16);
}
__device__ __forceinline__ float bf2f(unsigned short h){
  return __uint_as_float(((unsigned)h) << 16);
}
__device__ __forceinline__ void split2(float v, unsigned short* h, unsigned short* l){
  unsigned short hb = f2bf(v);
  *h = hb; *l = f2bf(v - bf2f(hb));
}

__device__ __forceinline__ float wredSum(float v){
#pragma unroll
  for(int o=32;o>0;o>>=1) v += __shfl_xor(v,o,64);
  return v;
}

// ---------------------------------------------------------------------------
__global__ __launch_bounds__(256) void ln_z_k(const float* __restrict__ skip,
    const float* __restrict__ g, const float* __restrict__ b,
    unsigned short* __restrict__ oh, unsigned short* __restrict__ ol,
    float* __restrict__ z)
{
  int row  = blockIdx.x*4 + (threadIdx.x>>6);
  int lane = threadIdx.x & 63;
  float4 v = ((const float4*)(skip + (size_t)row*DD))[lane];
  float s  = v.x+v.y+v.z+v.w;
  float sq = v.x*v.x+v.y*v.y+v.z*v.z+v.w*v.w;
  float si = v.x*sigm(v.x)+v.y*sigm(v.y)+v.z*sigm(v.z)+v.w*sigm(v.w);
  s = wredSum(s); sq = wredSum(sq); si = wredSum(si);
  float mean = s*(1.0f/DD);
  float var  = sq*(1.0f/DD) - mean*mean;
  float inv  = rsqrtf(var + 1e-5f);
  float4 gv = ((const float4*)g)[lane];
  float4 bv = ((const float4*)b)[lane];
  float o0 = (v.x-mean)*inv*gv.x + bv.x;
  float o1 = (v.y-mean)*inv*gv.y + bv.y;
  float o2 = (v.z-mean)*inv*gv.z + bv.z;
  float o3 = (v.w-mean)*inv*gv.w + bv.w;
  ushort4 hi, lo;
  split2(o0,&hi.x,&lo.x); split2(o1,&hi.y,&lo.y);
  split2(o2,&hi.z,&lo.z); split2(o3,&hi.w,&lo.w);
  ((ushort4*)(oh + (size_t)row*DD))[lane] = hi;
  ((ushort4*)(ol + (size_t)row*DD))[lane] = lo;
  if(lane==0) z[row] = sigm(si*(1.0f/DD));
}

__global__ __launch_bounds__(256) void rms_k(const float* __restrict__ x,
    const float* __restrict__ t,
    unsigned short* __restrict__ oh, unsigned short* __restrict__ ol)
{
  int row  = blockIdx.x*4 + (threadIdx.x>>6);
  int lane = threadIdx.x & 63;
  float4 v = ((const float4*)(x + (size_t)row*DD))[lane];
  float sq = v.x*v.x+v.y*v.y+v.z*v.z+v.w*v.w;
  sq = wredSum(sq);
  float inv = rsqrtf(sq*(1.0f/DD) + 1e-6f);
  float4 tv = ((const float4*)t)[lane];
  float o0 = v.x*inv*(1.0f+tv.x);
  float o1 = v.y*inv*(1.0f+tv.y);
  float o2 = v.z*inv*(1.0f+tv.z);
  float o3 = v.w*inv*(1.0f+tv.w);
  ushort4 hi, lo;
  split2(o0,&hi.x,&lo.x); split2(o1,&hi.y,&lo.y);
  split2(o2,&hi.z,&lo.z); split2(o3,&hi.w,&lo.w);
  ((ushort4*)(oh + (size_t)row*DD))[lane] = hi;
  ((ushort4*)(ol + (size_t)row*DD))[lane] = lo;
}

// hi-plane-only rms (consumers are A-hi-only GEMMs)
__global__ __launch_bounds__(256) void rms_h_k(const float* __restrict__ x,
    const float* __restrict__ t,
    unsigned short* __restrict__ oh)
{
  int row  = blockIdx.x*4 + (threadIdx.x>>6);
  int lane = threadIdx.x & 63;
  float4 v = ((const float4*)(x + (size_t)row*DD))[lane];
  float sq = v.x*v.x+v.y*v.y+v.z*v.z+v.w*v.w;
  sq = wredSum(sq);
  float inv = rsqrtf(sq*(1.0f/DD) + 1e-6f);
  float4 tv = ((const float4*)t)[lane];
  ushort4 hi;
  hi.x = f2bf(v.x*inv*(1.0f+tv.x));
  hi.y = f2bf(v.y*inv*(1.0f+tv.y));
  hi.z = f2bf(v.z*inv*(1.0f+tv.z));
  hi.w = f2bf(v.w*inv*(1.0f+tv.w));
  ((ushort4*)(oh + (size_t)row*DD))[lane] = hi;
}

// ---------------------------------------------------------------------------
struct TS  { const float* s; unsigned short* h; unsigned short* l; int K; int N; };
struct TS8 { TS t[8]; };

__global__ __launch_bounds__(256) void tsplit8_k(TS8 g){
  TS tt = g.t[blockIdx.y];
  int idx = blockIdx.x*256 + threadIdx.x;
  int tot = tt.K*tt.N;
  if(idx >= tot) return;
  int k = idx / tt.N;
  int n = idx - k*tt.N;
  float x = tt.s[idx];
  unsigned short hb = f2bf(x);
  unsigned short lb = f2bf(x - bf2f(hb));
  tt.h[(size_t)n*tt.K + k] = hb;
  tt.l[(size_t)n*tt.K + k] = lb;
}

// ---------------------------------------------------------------------------
// Split-bf16 MFMA GEMM.
// TERMS: 3 = AhBh+AhBl+AlBh ; 2 = AhBh+AhBl ; 1 = AhBh (pure bf16).
// MODE bits: 1=bias0, 2=gelu, 8=+Res. DUAL: gelu(A@B0+b0)*(A@B1+b1).
// OUT: 0 fp32; 1 hi/lo planes; 2 RoPE-q; 3 RoPE-k; 4 V^T bf16; 5 hi-only;
//      7 (DUAL) acc->RoPE-k planes + acc2->V^T bf16 into (ushort*)C.
// BN==128 + DUAL supported for TERMS==1 (B1 hi staged, no B1 lo).
// ---------------------------------------------------------------------------
template<int BN, int MODE, int DUAL, int OUT, int TERMS>
__global__ __launch_bounds__(256) void gemm_mfma(
    const unsigned short* __restrict__ Ah_g, const unsigned short* __restrict__ Al_g,
    const unsigned short* __restrict__ B0h, const unsigned short* __restrict__ B0l,
    const unsigned short* __restrict__ B1h, const unsigned short* __restrict__ B1l,
    const float* __restrict__ bias0, const float* __restrict__ bias1,
    const float* __restrict__ Res, float* __restrict__ C,
    unsigned short* __restrict__ Ch, unsigned short* __restrict__ Cl,
    int K, int lda, int ldc)
{
  constexpr int NT = BN/32;
  constexpr int ST = 40;
  __shared__ unsigned short Ash[128*ST];
  __shared__ unsigned short Asl[TERMS==3 ? 128*ST : 8];
  __shared__ unsigned short Bsh[BN*ST];
  __shared__ unsigned short Bsl[TERMS>=2 ? BN*ST : 8];
  __shared__ unsigned short B2h[DUAL?BN*ST:8];
  __shared__ unsigned short B2l[(DUAL && TERMS>=2)?BN*ST:8];

  const int tid  = threadIdx.x;
  const int lane = tid & 63, wave = tid >> 6;
  const int wm = wave >> 1, wn = wave & 1;
  const int bm = blockIdx.y*128, bn = blockIdx.x*BN;
  const int m16 = lane & 15, q = lane >> 4;

  f4acc acc[4][NT];
  f4acc acc2[DUAL?4:1][DUAL?NT:1];
#pragma unroll
  for(int i=0;i<4;i++)
#pragma unroll
    for(int j=0;j<NT;j++){
      acc[i][j] = (f4acc)0.f;
      if constexpr(DUAL) acc2[i][j] = (f4acc)0.f;
    }

  // staging map: 4 lanes per row; r0 in [0,64), chunk c0 in [0,4)
  const int r0 = tid >> 2, c0 = tid & 3;
  const int coff = c0*8;
  const int d0 = r0*ST + coff, d1 = (r0+64)*ST + coff;

  const unsigned short* pAh0 = Ah_g + (size_t)(bm+r0)*lda + coff;
  const unsigned short* pAh1 = pAh0 + (size_t)64*lda;
  const unsigned short* pAl0 = (TERMS==3) ? (Al_g + (size_t)(bm+r0)*lda + coff)
                                          : (const unsigned short*)nullptr;
  const unsigned short* pAl1 = (TERMS==3) ? (pAl0 + (size_t)64*lda)
                                          : (const unsigned short*)nullptr;
  const unsigned short *pB0h0=nullptr,*pB0h1=nullptr,*pB0l0=nullptr,*pB0l1=nullptr;
  const unsigned short *pB1h0=nullptr,*pB1h1=nullptr;
  const unsigned short *pBa=nullptr,*pBb=nullptr,*pBc=nullptr,*pBd=nullptr;
  if constexpr(BN==128){
    pB0h0 = B0h + (size_t)(bn+r0)*K + coff;  pB0h1 = pB0h0 + (size_t)64*K;
    if constexpr(TERMS>=2){
      pB0l0 = B0l + (size_t)(bn+r0)*K + coff;  pB0l1 = pB0l0 + (size_t)64*K;
    }
    if constexpr(DUAL){
      pB1h0 = B1h + (size_t)(bn+r0)*K + coff;  pB1h1 = pB1h0 + (size_t)64*K;
    }
  } else {
    pBa = B0h + (size_t)(bn+r0)*K + coff;
    if constexpr(TERMS>=2) pBb = B0l + (size_t)(bn+r0)*K + coff;
    if constexpr(DUAL){
      pBc = B1h + (size_t)(bn+r0)*K + coff;
      if constexpr(TERMS>=2) pBd = B1l + (size_t)(bn+r0)*K + coff;
    }
  }

  for(int k0 = 0; k0 < K; k0 += 32){
    // ---- A stage ----
    *(float4*)&Ash[d0] = *(const float4*)(pAh0 + k0);
    *(float4*)&Ash[d1] = *(const float4*)(pAh1 + k0);
    if constexpr(TERMS==3){
      *(float4*)&Asl[d0] = *(const float4*)(pAl0 + k0);
      *(float4*)&Asl[d1] = *(const float4*)(pAl1 + k0);
    }
    // ---- B stage ----
    if constexpr(BN==128){
      *(float4*)&Bsh[d0] = *(const float4*)(pB0h0 + k0);
      *(float4*)&Bsh[d1] = *(const float4*)(pB0h1 + k0);
      if constexpr(TERMS>=2){
        *(float4*)&Bsl[d0] = *(const float4*)(pB0l0 + k0);
        *(float4*)&Bsl[d1] = *(const float4*)(pB0l1 + k0);
      }
      if constexpr(DUAL){
        *(float4*)&B2h[d0] = *(const float4*)(pB1h0 + k0);
        *(float4*)&B2h[d1] = *(const float4*)(pB1h1 + k0);
      }
    } else {
      *(float4*)&Bsh[d0] = *(const float4*)(pBa + k0);
      if constexpr(TERMS>=2) *(float4*)&Bsl[d0] = *(const float4*)(pBb + k0);
      if constexpr(DUAL){
        *(float4*)&B2h[d0] = *(const float4*)(pBc + k0);
        if constexpr(TERMS>=2) *(float4*)&B2l[d0] = *(const float4*)(pBd + k0);
      }
    }
    __syncthreads();

    bfrag ah[4], al[TERMS==3?4:1], b0hf[NT], b0lf[TERMS>=2?NT:1];
    bfrag b1hf[DUAL?NT:1], b1lf[(DUAL&&TERMS>=2)?NT:1];
#pragma unroll
    for(int mi=0;mi<4;mi++){
      int row = wm*64 + mi*16 + m16;
      ah[mi] = *(const bfrag*)&Ash[row*ST + q*8];
      if constexpr(TERMS==3) al[mi] = *(const bfrag*)&Asl[row*ST + q*8];
    }
#pragma unroll
    for(int ni=0;ni<NT;ni++){
      int n = wn*(BN/2) + ni*16 + m16;
      b0hf[ni] = *(const bfrag*)&Bsh[n*ST + q*8];
      if constexpr(TERMS>=2) b0lf[ni] = *(const bfrag*)&Bsl[n*ST + q*8];
      if constexpr(DUAL){
        b1hf[ni] = *(const bfrag*)&B2h[n*ST + q*8];
        if constexpr(TERMS>=2) b1lf[ni] = *(const bfrag*)&B2l[n*ST + q*8];
      }
    }
#pragma unroll
    for(int mi=0;mi<4;mi++)
#pragma unroll
      for(int ni=0;ni<NT;ni++){
        acc[mi][ni] = __builtin_amdgcn_mfma_f32_16x16x32_bf16(ah[mi], b0hf[ni], acc[mi][ni],0,0,0);
        if constexpr(TERMS>=2)
          acc[mi][ni] = __builtin_amdgcn_mfma_f32_16x16x32_bf16(ah[mi], b0lf[ni], acc[mi][ni],0,0,0);
        if constexpr(TERMS==3)
          acc[mi][ni] = __builtin_amdgcn_mfma_f32_16x16x32_bf16(al[mi], b0hf[ni], acc[mi][ni],0,0,0);
        if constexpr(DUAL){
          acc2[mi][ni] = __builtin_amdgcn_mfma_f32_16x16x32_bf16(ah[mi], b1hf[ni], acc2[mi][ni],0,0,0);
          if constexpr(TERMS>=2)
            acc2[mi][ni] = __builtin_amdgcn_mfma_f32_16x16x32_bf16(ah[mi], b1lf[ni], acc2[mi][ni],0,0,0);
          if constexpr(TERMS==3)
            acc2[mi][ni] = __builtin_amdgcn_mfma_f32_16x16x32_bf16(al[mi], b1hf[ni], acc2[mi][ni],0,0,0);
        }
      }
    __syncthreads();
  }

  // ---- epilogue ----
  if constexpr(OUT==0 || OUT==1 || OUT==5){
#pragma unroll
    for(int ni=0;ni<NT;ni++){
      const int col = bn + wn*(BN/2) + ni*16 + m16;
      float bv0 = (MODE&1) ? bias0[col] : 0.f;
      float bv1 = DUAL ? bias1[col] : 0.f;
#pragma unroll
      for(int mi=0;mi<4;mi++){
#pragma unroll
        for(int r=0;r<4;r++){
          const int row = bm + wm*64 + mi*16 + q*4 + r;
          float v = acc[mi][ni][r] + bv0;
          if constexpr(DUAL){
            float v2 = acc2[mi][ni][r] + bv1;
            v = geluf(v) * v2;
          } else if(MODE&2){
            v = geluf(v);
          }
          if(MODE&8) v += Res[(size_t)row*ldc + col];
          if constexpr(OUT==0){
            C[(size_t)row*ldc + col] = v;
          } else if constexpr(OUT==1){
            unsigned short hb = f2bf(v);
            Ch[(size_t)row*ldc + col] = hb;
            Cl[(size_t)row*ldc + col] = f2bf(v - bf2f(hb));
          } else {
            Ch[(size_t)row*ldc + col] = f2bf(v);
          }
        }
      }
    }
  } else if constexpr(OUT==2){
    const int hb = bn + wn*64;
    const float p = (float)m16;
    const float invf = __expf(-p * 0.575646273248511f);
#pragma unroll
    for(int mi=0;mi<4;mi++){
#pragma unroll
      for(int r=0;r<4;r++){
        const int row = bm + wm*64 + mi*16 + q*4 + r;
        const int s = row & (SS-1);
        float t = (float)s * invf;
        float sn, cs; __sincosf(t, &sn, &cs);
        float x1 = acc[mi][0][r], x2 = acc[mi][1][r];
        float v0 = (x1*cs - x2*sn)*0.125f;
        float v1 = (x2*cs + x1*sn)*0.125f;
        float v2 = acc[mi][2][r]*0.125f;
        float v3 = acc[mi][3][r]*0.125f;
        size_t base = (size_t)row*ldc + hb;
        unsigned short hh;
        hh=f2bf(v0); Ch[base+m16]=hh;    Cl[base+m16]   =f2bf(v0-bf2f(hh));
        hh=f2bf(v1); Ch[base+16+m16]=hh; Cl[base+16+m16]=f2bf(v1-bf2f(hh));
        hh=f2bf(v2); Ch[base+32+m16]=hh; Cl[base+32+m16]=f2bf(v2-bf2f(hh));
        hh=f2bf(v3); Ch[base+48+m16]=hh; Cl[base+48+m16]=f2bf(v3-bf2f(hh));
      }
    }
  } else if constexpr(OUT==3){
    const float p = (float)m16;
    const float invf = __expf(-p * 0.575646273248511f);
#pragma unroll
    for(int mi=0;mi<4;mi++){
#pragma unroll
      for(int r=0;r<4;r++){
        const int row = bm + wm*64 + mi*16 + q*4 + r;
        const int s = row & (SS-1);
        float v0, v1;
        if(wn==0){
          float t = (float)s * invf;
          float sn, cs; __sincosf(t, &sn, &cs);
          float x1 = acc[mi][0][r], x2 = acc[mi][1][r];
          v0 = x1*cs - x2*sn;
          v1 = x2*cs + x1*sn;
        } else {
          v0 = acc[mi][0][r]; v1 = acc[mi][1][r];
        }
        size_t base = (size_t)row*ldc + wn*32;
        unsigned short hh;
        hh=f2bf(v0); Ch[base+m16]=hh;    Cl[base+m16]   =f2bf(v0-bf2f(hh));
        hh=f2bf(v1); Ch[base+16+m16]=hh; Cl[base+16+m16]=f2bf(v1-bf2f(hh));
      }
    }
  } else if constexpr(OUT==4){
#pragma unroll
    for(int ni=0;ni<NT;ni++){
      const int col = wn*32 + ni*16 + m16;
#pragma unroll
      for(int mi=0;mi<4;mi++){
        const int rowb = bm + wm*64 + mi*16 + q*4;
        const int b = rowb >> 12, sl = rowb & (SS-1);
        ushort4 hv;
        hv.x = f2bf(acc[mi][ni][0]); hv.y = f2bf(acc[mi][ni][1]);
        hv.z = f2bf(acc[mi][ni][2]); hv.w = f2bf(acc[mi][ni][3]);
        *(ushort4*)(Ch + ((size_t)(b*64 + col))*SS + sl) = hv;
      }
    }
  } else if constexpr(OUT==7){
    // acc -> RoPE-k hi/lo planes (ldc=HDIM); acc2 -> V^T bf16 into (ushort*)C
    const float p = (float)m16;
    const float invf = __expf(-p * 0.575646273248511f);
#pragma unroll
    for(int mi=0;mi<4;mi++){
#pragma unroll
      for(int r=0;r<4;r++){
        const int row = bm + wm*64 + mi*16 + q*4 + r;
        const int s = row & (SS-1);
        float v0, v1;
        if(wn==0){
          float t = (float)s * invf;
          float sn, cs; __sincosf(t, &sn, &cs);
          float x1 = acc[mi][0][r], x2 = acc[mi][1][r];
          v0 = x1*cs - x2*sn;
          v1 = x2*cs + x1*sn;
        } else {
          v0 = acc[mi][0][r]; v1 = acc[mi][1][r];
        }
        size_t base = (size_t)row*ldc + wn*32;
        unsigned short hh;
        hh=f2bf(v0); Ch[base+m16]=hh;    Cl[base+m16]   =f2bf(v0-bf2f(hh));
        hh=f2bf(v1); Ch[base+16+m16]=hh; Cl[base+16+m16]=f2bf(v1-bf2f(hh));
      }
    }
    if constexpr(DUAL){
      unsigned short* Cv = (unsigned short*)C;
#pragma unroll
      for(int ni=0;ni<NT;ni++){
        const int col = wn*32 + ni*16 + m16;
#pragma unroll
        for(int mi=0;mi<4;mi++){
          const int rowb = bm + wm*64 + mi*16 + q*4;
          const int b = rowb >> 12, sl = rowb & (SS-1);
          ushort4 hv;
          hv.x = f2bf(acc2[mi][ni][0]); hv.y = f2bf(acc2[mi][ni][1]);
          hv.z = f2bf(acc2[mi][ni][2]); hv.w = f2bf(acc2[mi][ni][3]);
          *(ushort4*)(Cv + ((size_t)(b*64 + col))*SS + sl) = hv;
        }
      }
    }
  }
}

// ---------------------------------------------------------------------------
// Fused conv + RG-LRU gate path on MFMA. Per block: one head, 128 rows.
// ---------------------------------------------------------------------------
__global__ __launch_bounds__(256) void gates_conv_k(
    const float* __restrict__ X,      // lx output [RR2][DD] (pre-conv)
    const float* __restrict__ cw, const float* __restrict__ cb,
    const unsigned short* __restrict__ igth, const unsigned short* __restrict__ igtl,
    const unsigned short* __restrict__ agth, const unsigned short* __restrict__ agtl,
    const float* __restrict__ igb, const float* __restrict__ agb,
    const float* __restrict__ ap,
    float* __restrict__ Aout, float* __restrict__ Bout)
{
  constexpr int ST = 72;
  __shared__ unsigned short Ash[128*ST];
  __shared__ unsigned short Asl[128*ST];

  const int h  = blockIdx.x;          // head
  const int bm = blockIdx.y*128;
  const int tid = threadIdx.x;
  const int lane = tid & 63, wave = tid >> 6;
  const int wm = wave >> 1, wn = wave & 1;
  const int m16 = lane & 15, q = lane >> 4;

  // ---- conv + split stage: 16 strips x 8 rows, 16 col-groups x 4 cols ----
  {
    const int strip = tid >> 4;
    const int cg = (tid & 15)*4;
    const int col0 = h*HDIM + cg;
    const int r0 = bm + strip*8;
    float h0[4], h1[4], h2[4];
#pragma unroll
    for(int i=0;i<3;i++){
      int rr = r0 - 3 + i;
      int rc = rr < 0 ? 0 : rr;
      float4 hv = *(const float4*)(X + (size_t)rc*DD + col0);
      float* dst = (i==0)?h0:((i==1)?h1:h2);
      dst[0]=hv.x; dst[1]=hv.y; dst[2]=hv.z; dst[3]=hv.w;
    }
    float4 w0v = *(const float4*)(cw + 0*DD + col0);
    float4 w1v = *(const float4*)(cw + 1*DD + col0);
    float4 w2v = *(const float4*)(cw + 2*DD + col0);
    float4 w3v = *(const float4*)(cw + 3*DD + col0);
    float4 bbv = *(const float4*)(cb + col0);
    const float* w0 = (const float*)&w0v; const float* w1 = (const float*)&w1v;
    const float* w2 = (const float*)&w2v; const float* w3 = (const float*)&w3v;
    const float* bb = (const float*)&bbv;
    for(int rr=0; rr<8; rr++){
      const int r = r0 + rr;
      const int s = r & (SS-1);
      float4 cv = *(const float4*)(X + (size_t)r*DD + col0);
      float cur[4]; cur[0]=cv.x; cur[1]=cv.y; cur[2]=cv.z; cur[3]=cv.w;
      ushort4 hi, lo;
      unsigned short* hp = (unsigned short*)&hi;
      unsigned short* lp = (unsigned short*)&lo;
#pragma unroll
      for(int j=0;j<4;j++){
        float acc = bb[j] + w3[j]*cur[j];
        if(s>=1) acc += w2[j]*h2[j];
        if(s>=2) acc += w1[j]*h1[j];
        if(s>=3) acc += w0[j]*h0[j];
        unsigned short hb = f2bf(acc);
        hp[j] = hb; lp[j] = f2bf(acc - bf2f(hb));
      }
      const int dst = (strip*8+rr)*ST + cg;
      *(ushort4*)&Ash[dst] = hi;
      *(ushort4*)&Asl[dst] = lo;
#pragma unroll
      for(int j=0;j<4;j++){ h0[j]=h1[j]; h1[j]=h2[j]; h2[j]=cur[j]; }
    }
  }
  __syncthreads();

  f4acc accI[4][2], accA[4][2];
#pragma unroll
  for(int i=0;i<4;i++)
#pragma unroll
    for(int j=0;j<2;j++){ accI[i][j]=(f4acc)0.f; accA[i][j]=(f4acc)0.f; }

  const size_t wbase = (size_t)h*HDIM*HDIM;
#pragma unroll
  for(int ks=0;ks<2;ks++){
    bfrag ah[4], al[4];
#pragma unroll
    for(int mi=0;mi<4;mi++){
      const int row = wm*64 + mi*16 + m16;
      ah[mi] = *(const bfrag*)&Ash[row*ST + ks*32 + q*8];
      al[mi] = *(const bfrag*)&Asl[row*ST + ks*32 + q*8];
    }
#pragma unroll
    for(int ni=0;ni<2;ni++){
      const size_t bo = wbase + (size_t)(wn*32 + ni*16 + m16)*HDIM + ks*32 + q*8;
      bfrag bIh = *(const bfrag*)(igth + bo);
      bfrag bIl = *(const bfrag*)(igtl + bo);
      bfrag bAh = *(const bfrag*)(agth + bo);
      bfrag bAl = *(const bfrag*)(agtl + bo);
#pragma unroll
      for(int mi=0;mi<4;mi++){
        accI[mi][ni] = __builtin_amdgcn_mfma_f32_16x16x32_bf16(ah[mi], bIh, accI[mi][ni],0,0,0);
        accI[mi][ni] = __builtin_amdgcn_mfma_f32_16x16x32_bf16(ah[mi], bIl, accI[mi][ni],0,0,0);
        accI[mi][ni] = __builtin_amdgcn_mfma_f32_16x16x32_bf16(al[mi], bIh, accI[mi][ni],0,0,0);
        accA[mi][ni] = __builtin_amdgcn_mfma_f32_16x16x32_bf16(ah[mi], bAh, accA[mi][ni],0,0,0);
        accA[mi][ni] = __builtin_amdgcn_mfma_f32_16x16x32_bf16(ah[mi], bAl, accA[mi][ni],0,0,0);
        accA[mi][ni] = __builtin_amdgcn_mfma_f32_16x16x32_bf16(al[mi], bAh, accA[mi][ni],0,0,0);
      }
    }
  }

  // ---- gate epilogue ----
#pragma unroll
  for(int ni=0;ni<2;ni++){
    const int cl  = wn*32 + ni*16 + m16;     // col within head
    const int col = h*HDIM + cl;
    const float bI = igb[col], bA = agb[col];
    const float apv = ap[col];
    const float sp = (apv > 20.f) ? apv : log1pf(expf(apv));
#pragma unroll
    for(int mi=0;mi<4;mi++){
#pragma unroll
      for(int r=0;r<4;r++){
        const int lrow = wm*64 + mi*16 + q*4 + r;
        const int row = bm + lrow;
        const int s = row & (SS-1);
        float gx = 1.f/(1.f + __expf(-(accI[mi][ni][r] + bI)));
        float ga = 1.f/(1.f + __expf(-(accA[mi][ni][r] + bA)));
        float la = -8.f * ga * sp;
        float a_ = __expf(la);
        float mult = (s==0) ? 1.f : sqrtf(fmaxf(1.f - __expf(2.f*la), 0.f));
        float x = bf2f(Ash[lrow*ST + cl]) + bf2f(Asl[lrow*ST + cl]);
        Aout[(size_t)row*DD + col] = a_;
        Bout[(size_t)row*DD + col] = x * gx * mult;
      }
    }
  }
}

__global__ __launch_bounds__(256) void scan1_k(const float* __restrict__ A,
    const float* __restrict__ Bv, float* __restrict__ csa, float* __restrict__ csb)
{
  int idx = blockIdx.x*256 + threadIdx.x;
  int d = idx & (DD-1);
  int c = (idx >> 8) & (NCH-1);
  int b = idx >> 14;
  size_t base = ((size_t)b*SS + (size_t)c*CH)*DD + d;
  float Aa = 1.f, Bb_ = 0.f;
  for(int t=0;t<CH;t++){
    float a  = A [base + (size_t)t*DD];
    float bb = Bv[base + (size_t)t*DD];
    Aa  = a*Aa;
    Bb_ = a*Bb_ + bb;
  }
  csa[idx] = Aa; csb[idx] = Bb_;
}

__global__ __launch_bounds__(256) void scan2_k(const float* __restrict__ csa,
    float* __restrict__ csb)
{
  int idx = blockIdx.x*256 + threadIdx.x;
  int d = idx & (DD-1);
  int b = idx >> 8;
  float h = 0.f;
  for(int c=0;c<NCH;c++){
    size_t i = ((size_t)b*NCH + c)*DD + d;
    float Aa = csa[i], Bb_ = csb[i];
    csb[i] = h;
    h = Aa*h + Bb_;
  }
}

__global__ __launch_bounds__(256) void scan3_k(const float* __restrict__ A,
    const float* __restrict__ Bv, const float* __restrict__ csb,
    const unsigned short* __restrict__ Yh,
    unsigned short* __restrict__ Hh)
{
  int idx = blockIdx.x*256 + threadIdx.x;
  int d = idx & (DD-1);
  int c = (idx >> 8) & (NCH-1);
  int b = idx >> 14;
  size_t base = ((size_t)b*SS + (size_t)c*CH)*DD + d;
  float h = csb[idx];
  for(int t=0;t<CH;t++){
    float a  = A [base + (size_t)t*DD];
    float bb = Bv[base + (size_t)t*DD];
    h = a*h + bb;
    float v = h * bf2f(Yh[base + (size_t)t*DD]);
    Hh[base + (size_t)t*DD] = f2bf(v);
  }
}

// ---------------------------------------------------------------------------
#define AST 72
__global__ __launch_bounds__(256) void attn_k(
    const unsigned short* __restrict__ Qh, const unsigned short* __restrict__ Ql,
    const unsigned short* __restrict__ Kh, const unsigned short* __restrict__ Kl,
    const unsigned short* __restrict__ Vt,
    unsigned short* __restrict__ Oh, unsigned short* __restrict__ Ol)
{
  __shared__ unsigned short Ksh[64*AST], Ksl[64*AST], Vsh[64*AST];
  __shared__ unsigned short Ps[4*16*AST];

  const int qt = blockIdx.x & 3, n = blockIdx.x >> 2;
  const int h = blockIdx.y, b = blockIdx.z;
  const int tid = threadIdx.x;
  const int lane = tid & 63, w = tid >> 6;
  const int m16 = lane & 15, q = lane >> 4;
  const int s0 = n*WNN + qt*64;

  const size_t qro = ((size_t)(b*SS + s0 + w*16 + m16))*DD + h*HDIM + q*8;
  bfrag qh0 = *(const bfrag*)(Qh + qro);
  bfrag qh1 = *(const bfrag*)(Qh + qro + 32);
  bfrag ql0 = *(const bfrag*)(Ql + qro);
  bfrag ql1 = *(const bfrag*)(Ql + qro + 32);

  float mrow[4], lrow[4];
  f4acc oacc[4];
#pragma unroll
  for(int i=0;i<4;i++){ mrow[i]=-3.0e38f; lrow[i]=0.f; oacc[i]=(f4acc)0.f; }

  const int ktlo = (n==0) ? 4 : qt;
  const int kthi = qt + 4;
  const int sr = tid >> 2, sc = tid & 3;

  for(int kt=ktlo; kt<=kthi; kt++){
    const int kbase = (n-1)*WNN + kt*64;
#pragma unroll
    for(int cc=0; cc<2; cc++){
      int g = sc + cc*4;
      *(float4*)&Ksh[sr*AST + g*8] =
        *(const float4*)(Kh + (size_t)(b*SS + kbase + sr)*HDIM + g*8);
      *(float4*)&Ksl[sr*AST + g*8] =
        *(const float4*)(Kl + (size_t)(b*SS + kbase + sr)*HDIM + g*8);
      *(float4*)&Vsh[sr*AST + g*8] =
        *(const float4*)(Vt + ((size_t)(b*64 + sr))*SS + kbase + g*8);
    }
    __syncthreads();

    f4acc sacc[4];
#pragma unroll
    for(int nt=0;nt<4;nt++) sacc[nt] = (f4acc)0.f;
#pragma unroll
    for(int nt=0;nt<4;nt++){
      const int kr = (nt*16+m16)*AST;
      bfrag kh0 = *(const bfrag*)&Ksh[kr + q*8];
      bfrag kh1 = *(const bfrag*)&Ksh[kr + 32 + q*8];
      bfrag kl0 = *(const bfrag*)&Ksl[kr + q*8];
      bfrag kl1 = *(const bfrag*)&Ksl[kr + 32 + q*8];
      sacc[nt] = __builtin_amdgcn_mfma_f32_16x16x32_bf16(qh0, kh0, sacc[nt],0,0,0);
      sacc[nt] = __builtin_amdgcn_mfma_f32_16x16x32_bf16(qh0, kl0, sacc[nt],0,0,0);
      sacc[nt] = __builtin_amdgcn_mfma_f32_16x16x32_bf16(ql0, kh0, sacc[nt],0,0,0);
      sacc[nt] = __builtin_amdgcn_mfma_f32_16x16x32_bf16(qh1, kh1, sacc[nt],0,0,0);
      sacc[nt] = __builtin_amdgcn_mfma_f32_16x16x32_bf16(qh1, kl1, sacc[nt],0,0,0);
      sacc[nt] = __builtin_amdgcn_mfma_f32_16x16x32_bf16(ql1, kh1, sacc[nt],0,0,0);
    }

    const bool needlo = (kt == qt+4);
    const bool needhi = (kt == qt);
#pragma unroll
    for(int r=0;r<4;r++){
      int qp = qt*64 + w*16 + q*4 + r;
      float sv[4];
      float tm = -3.0e38f;
#pragma unroll
      for(int nt=0;nt<4;nt++){
        float scv = sacc[nt][r];
        if(needlo || needhi){
          int kj = kt*64 + nt*16 + m16;
          int diff = qp + WNN - kj;
          bool ok = (!needlo || diff >= 0) && (!needhi || diff <= WNN);
          scv = ok ? scv : -3.0e38f;
        }
        sv[nt] = scv;
        tm = fmaxf(tm, scv);
      }
#pragma unroll
      for(int off=1; off<16; off<<=1) tm = fmaxf(tm, __shfl_xor(tm, off, 64));
      float mn = fmaxf(mrow[r], tm);
      float alpha = __expf(mrow[r]-mn);
      float rs = 0.f;
#pragma unroll
      for(int nt=0;nt<4;nt++){
        float pp = __expf(sv[nt]-mn);
        rs += pp;
        Ps[w*16*AST + (q*4+r)*AST + nt*16 + m16] = f2bf(pp);
      }
#pragma unroll
      for(int off=1; off<16; off<<=1) rs += __shfl_xor(rs, off, 64);
      lrow[r] = lrow[r]*alpha + rs;
      mrow[r] = mn;
#pragma unroll
      for(int nt=0;nt<4;nt++) oacc[nt][r] *= alpha;
    }

#pragma unroll
    for(int s=0;s<2;s++){
      bfrag pa = *(const bfrag*)&Ps[w*16*AST + m16*AST + s*32 + q*8];
#pragma unroll
      for(int nt=0;nt<4;nt++){
        bfrag vh_ = *(const bfrag*)&Vsh[(nt*16+m16)*AST + s*32 + q*8];
        oacc[nt] = __builtin_amdgcn_mfma_f32_16x16x32_bf16(pa, vh_, oacc[nt],0,0,0);
      }
    }
    __syncthreads();
  }

#pragma unroll
  for(int r=0;r<4;r++){
    float invl = 1.f/lrow[r];
    const size_t rowbase = ((size_t)(b*SS + s0 + w*16 + q*4 + r))*DD + h*HDIM;
#pragma unroll
    for(int nt=0;nt<4;nt++){
      float v = oacc[nt][r]*invl;
      unsigned short hb = f2bf(v);
      Oh[rowbase + nt*16 + m16] = hb;
      Ol[rowbase + nt*16 + m16] = f2bf(v - bf2f(hb));
    }
  }
}

__global__ __launch_bounds__(256) void comb_k(const float* __restrict__ of,
    const float* __restrict__ ob, const float* __restrict__ z,
    const float* __restrict__ skip, float* __restrict__ out)
{
  int idx = blockIdx.x*256 + threadIdx.x;
  int r = idx >> 8;
  out[idx] = z[r]*(of[idx]+ob[idx]) + skip[idx];
}

// ---------------------------------------------------------------------------
struct Params {
  const float *ln_gamma,*ln_beta,*proj_w,*proj_b,*fconv_w,*fconv_b,*bconv_w,*bconv_b,
    *rn0_t,*rn0_c,*ly_w,*ly_b,*lx_w,*lx_b,*lo_w,*lo_b,*c1d_w,*c1d_b,*a_param,
    *ig_w,*ig_b,*ag_w,*ag_b,*mlp0_up_w,*mlp0_up_b,*mlp0_dn_w,*mlp0_dn_b,
    *rn1_t,*rn1_c,*q_w,*k_w,*v_w,*o_w,*o_b,*mlp1_up_w,*mlp1_up_b,*mlp1_dn_w,*mlp1_dn_b;
};

struct WSplit {
  unsigned short *proj_h,*proj_l,*fconv_h,*fconv_l,*bconv_h,*bconv_l,
    *ly_h,*ly_l,*lx_h,*lx_l,*lo_h,*lo_l,*q_h,*q_l,*o_h,*o_l,
    *k_h,*k_l,*v_h,*v_l,
    *up0a_h,*up0a_l,*up0b_h,*up0b_l,*up1a_h,*up1a_l,*up1b_h,*up1b_l,
    *dn0_h,*dn0_l,*dn1_h,*dn1_l,
    *igt_h,*igt_l,*agt_h,*agt_l;
};

#define USN ((unsigned short*)nullptr)

extern "C" void kernel_launch(void* const* d_in, const int* in_sizes, int n_in,
                              void* d_out, int out_size, void* d_ws, size_t ws_size,
                              hipStream_t stream)
{
  (void)in_sizes; (void)n_in; (void)out_size; (void)ws_size;
  const float* skip = (const float*)d_in[0];
  Params p;
  p.ln_gamma  =(const float*)d_in[1];  p.ln_beta  =(const float*)d_in[2];
  p.proj_w    =(const float*)d_in[3];  p.proj_b   =(const float*)d_in[4];
  p.fconv_w   =(const float*)d_in[5];  p.fconv_b  =(const float*)d_in[6];
  p.bconv_w   =(const float*)d_in[7];  p.bconv_b  =(const float*)d_in[8];
  p.rn0_t     =(const float*)d_in[9];  p.rn0_c    =(const float*)d_in[10];
  p.ly_w      =(const float*)d_in[11]; p.ly_b     =(const float*)d_in[12];
  p.lx_w      =(const float*)d_in[13]; p.lx_b     =(const float*)d_in[14];
  p.lo_w      =(const float*)d_in[15]; p.lo_b     =(const float*)d_in[16];
  p.c1d_w     =(const float*)d_in[17]; p.c1d_b    =(const float*)d_in[18];
  p.a_param   =(const float*)d_in[19];
  p.ig_w      =(const float*)d_in[20]; p.ig_b     =(const float*)d_in[21];
  p.ag_w      =(const float*)d_in[22]; p.ag_b     =(const float*)d_in[23];
  p.mlp0_up_w =(const float*)d_in[24]; p.mlp0_up_b=(const float*)d_in[25];
  p.mlp0_dn_w =(const float*)d_in[26]; p.mlp0_dn_b=(const float*)d_in[27];
  p.rn1_t     =(const float*)d_in[28]; p.rn1_c    =(const float*)d_in[29];
  p.q_w       =(const float*)d_in[30]; p.k_w      =(const float*)d_in[31];
  p.v_w       =(const float*)d_in[32]; p.o_w      =(const float*)d_in[33];
  p.o_b       =(const float*)d_in[34];
  p.mlp1_up_w =(const float*)d_in[35]; p.mlp1_up_b=(const float*)d_in[36];
  p.mlp1_dn_w =(const float*)d_in[37]; p.mlp1_dn_b=(const float*)d_in[38];

  float* ws = (float*)d_ws;
  const size_t RD  = (size_t)RR*DD;
  const size_t PD2 = (size_t)RR2*DD;
  size_t off = 0;
  float* Z   = ws + off; off += 16384;
  float* XB2 = ws + off; off += 2*RD;
  float* CV2 = ws + off; off += 2*RD;
  float* W1  = ws + off; off += 2*RD;
  float* W2  = ws + off; off += 2*RD;
  float* W3  = ws + off; off += RD;
  float* W4  = ws + off; off += 2*RD;

  float* CSA = CV2;
  float* CSB = CV2 + 8*NCH*DD;

  unsigned short* NPh = (unsigned short*)W4;  unsigned short* NPl = NPh + PD2;
  float* BT = W4;                              // bterm fp32 (gates output)
  unsigned short* HYh = (unsigned short*)W1;   // scan3 output (hi only)
  unsigned short* X0h = (unsigned short*)W1;  unsigned short* X0l = X0h + (size_t)RR*DD;
  float* XR2 = W1;
  unsigned short* Qph = (unsigned short*)W1;  unsigned short* Qpl = Qph + PD2;
  float* Abuf = W2;
  unsigned short* P2h = (unsigned short*)W2;  unsigned short* P2l = P2h + PD2;
  unsigned short* Yh  = (unsigned short*)W3;
  unsigned short* KPh = (unsigned short*)W3;  unsigned short* KPl = KPh + (size_t)RR2*HDIM;
  unsigned short* Vt  = KPl + (size_t)RR2*HDIM;
  unsigned short* ACTh = (unsigned short*)W1;
  float* OUT2 = XB2;

  unsigned short* sp = (unsigned short*)(ws + off);
  WSplit w;
  auto alloc_s = [&](size_t n){ unsigned short* r = sp; sp += n; return r; };
  const size_t SDD = (size_t)DD*DD, SKV = (size_t)DD*HDIM, SUP = (size_t)DD*EE;
  const size_t SBD = (size_t)HH*HDIM*HDIM;
  w.proj_h=alloc_s(SDD);  w.proj_l=alloc_s(SDD);
  w.fconv_h=alloc_s(SDD); w.fconv_l=alloc_s(SDD);
  w.bconv_h=alloc_s(SDD); w.bconv_l=alloc_s(SDD);
  w.ly_h=alloc_s(SDD);    w.ly_l=alloc_s(SDD);
  w.lx_h=alloc_s(SDD);    w.lx_l=alloc_s(SDD);
  w.lo_h=alloc_s(SDD);    w.lo_l=alloc_s(SDD);
  w.q_h=alloc_s(SDD);     w.q_l=alloc_s(SDD);
  w.o_h=alloc_s(SDD);     w.o_l=alloc_s(SDD);
  w.k_h=alloc_s(SKV);     w.k_l=alloc_s(SKV);
  w.v_h=alloc_s(SKV);     w.v_l=alloc_s(SKV);
  w.up0a_h=alloc_s(SUP);  w.up0a_l=alloc_s(SUP);
  w.up0b_h=alloc_s(SUP);  w.up0b_l=alloc_s(SUP);
  w.up1a_h=alloc_s(SUP);  w.up1a_l=alloc_s(SUP);
  w.up1b_h=alloc_s(SUP);  w.up1b_l=alloc_s(SUP);
  w.dn0_h=alloc_s(SUP);   w.dn0_l=alloc_s(SUP);
  w.dn1_h=alloc_s(SUP);   w.dn1_l=alloc_s(SUP);
  w.igt_h=alloc_s(SBD);   w.igt_l=alloc_s(SBD);
  w.agt_h=alloc_s(SBD);   w.agt_l=alloc_s(SBD);

  dim3 blk(256);
  dim3 g2(2,128,1);
  dim3 g2m(2,256,1), g64m(1,256,1), gdual(6,256,1);
  dim3 ggm(HH, RR2/128, 1);

  {
    TS8 ga;
    ga.t[0] = {p.proj_w,  w.proj_h,  w.proj_l,  DD, DD};
    ga.t[1] = {p.fconv_w, w.fconv_h, w.fconv_l, DD, DD};
    ga.t[2] = {p.bconv_w, w.bconv_h, w.bconv_l, DD, DD};
    ga.t[3] = {p.ly_w,    w.ly_h,    w.ly_l,    DD, DD};
    ga.t[4] = {p.lx_w,    w.lx_h,    w.lx_l,    DD, DD};
    ga.t[5] = {p.lo_w,    w.lo_h,    w.lo_l,    DD, DD};
    ga.t[6] = {p.q_w,     w.q_h,     w.q_l,     DD, DD};
    ga.t[7] = {p.o_w,     w.o_h,     w.o_l,     DD, DD};
    tsplit8_k<<<dim3(DD*DD/256, 8), blk, 0, stream>>>(ga);
    TS8 gb;
    gb.t[0] = {p.k_w,              w.k_h,    w.k_l,    DD, HDIM};
    gb.t[1] = {p.v_w,              w.v_h,    w.v_l,    DD, HDIM};
    gb.t[2] = {p.mlp0_up_w,        w.up0a_h, w.up0a_l, DD, EE};
    gb.t[3] = {p.mlp0_up_w+(size_t)DD*EE, w.up0b_h, w.up0b_l, DD, EE};
    gb.t[4] = {p.mlp1_up_w,        w.up1a_h, w.up1a_l, DD, EE};
    gb.t[5] = {p.mlp1_up_w+(size_t)DD*EE, w.up1b_h, w.up1b_l, DD, EE};
    gb.t[6] = {p.mlp0_dn_w,        w.dn0_h,  w.dn0_l,  EE, DD};
    gb.t[7] = {p.mlp1_dn_w,        w.dn1_h,  w.dn1_l,  EE, DD};
    tsplit8_k<<<dim3(DD*EE/256, 8), blk, 0, stream>>>(gb);
    TS8 gc;
    for(int h=0;h<HH;h++){
      gc.t[h]   = {p.ig_w + (size_t)h*HDIM*HDIM, w.igt_h + (size_t)h*HDIM*HDIM,
                   w.igt_l + (size_t)h*HDIM*HDIM, HDIM, HDIM};
      gc.t[4+h] = {p.ag_w + (size_t)h*HDIM*HDIM, w.agt_h + (size_t)h*HDIM*HDIM,
                   w.agt_l + (size_t)h*HDIM*HDIM, HDIM, HDIM};
    }
    tsplit8_k<<<dim3(HDIM*HDIM/256, 8), blk, 0, stream>>>(gc);
  }

  // ---- prologue ----
  ln_z_k<<<RR/4, blk, 0, stream>>>(skip, p.ln_gamma, p.ln_beta, NPh, NPl, Z);
  gemm_mfma<128,1,0,1,3><<<g2,blk,0,stream>>>(NPh,NPl, w.proj_h,w.proj_l, USN,USN,
      p.proj_b,nullptr,nullptr, nullptr, X0h, X0l, DD,DD,DD);
  gemm_mfma<128,1,0,0,3><<<g2,blk,0,stream>>>(X0h,X0l, w.fconv_h,w.fconv_l, USN,USN,
      p.fconv_b,nullptr,nullptr, XB2, USN,USN, DD,DD,DD);
  gemm_mfma<128,1,0,0,3><<<g2,blk,0,stream>>>(X0h,X0l, w.bconv_h,w.bconv_l, USN,USN,
      p.bconv_b,nullptr,nullptr, XB2 + RD, USN,USN, DD,DD,DD);

  // ---- residual block 0: recurrent (merged, M=32768) ----
  rms_h_k<<<RR2/4, blk, 0, stream>>>(XB2, p.rn0_t, NPh);
  gemm_mfma<128,3,0,5,2><<<g2m,blk,0,stream>>>(NPh,USN, w.ly_h,w.ly_l, USN,USN,
      p.ly_b,nullptr,nullptr, nullptr, Yh, USN, DD,DD,DD);
  gemm_mfma<128,1,0,0,2><<<g2m,blk,0,stream>>>(NPh,USN, w.lx_h,w.lx_l, USN,USN,
      p.lx_b,nullptr,nullptr, XR2, USN,USN, DD,DD,DD);
  gates_conv_k<<<ggm,blk,0,stream>>>(XR2, p.c1d_w, p.c1d_b,
      w.igt_h, w.igt_l, w.agt_h, w.agt_l, p.ig_b, p.ag_b, p.a_param, Abuf, BT);
  scan1_k<<<8*NCH*DD/256, blk,0,stream>>>(Abuf, BT, CSA, CSB);
  scan2_k<<<8*DD/256, blk,0,stream>>>(CSA, CSB);
  scan3_k<<<8*NCH*DD/256, blk,0,stream>>>(Abuf, BT, CSB, Yh, HYh);
  gemm_mfma<128,9,0,0,2><<<g2m,blk,0,stream>>>(HYh,USN, w.lo_h,w.lo_l, USN,USN,
      p.lo_b,nullptr, XB2, CV2, USN,USN, DD,DD,DD);
  rms_h_k<<<RR2/4,blk,0,stream>>>(CV2, p.rn0_c, NPh);
  gemm_mfma<128,1,1,5,1><<<gdual,blk,0,stream>>>(NPh,USN, w.up0a_h,USN,
      w.up0b_h,USN, p.mlp0_up_b, p.mlp0_up_b+EE, nullptr, nullptr,
      ACTh, USN, DD,DD,EE);
  gemm_mfma<128,9,0,0,2><<<g2m,blk,0,stream>>>(ACTh,USN, w.dn0_h,w.dn0_l, USN,USN,
      p.mlp0_dn_b,nullptr, CV2, XB2, USN,USN, EE,EE,DD);

  // ---- residual block 1: local attention (merged) ----
  rms_k<<<RR2/4,blk,0,stream>>>(XB2, p.rn1_t, NPh, NPl);
  gemm_mfma<128,0,0,2,2><<<g2m,blk,0,stream>>>(NPh,USN, w.q_h,w.q_l, USN,USN,
      nullptr,nullptr,nullptr, nullptr, Qph, Qpl, DD,DD,DD);
  gemm_mfma<64,0,1,7,3><<<g64m,blk,0,stream>>>(NPh,NPl, w.k_h,w.k_l, w.v_h,w.v_l,
      nullptr,nullptr,nullptr, (float*)Vt, KPh, KPl, DD,DD,HDIM);
  attn_k<<<dim3(64,4,8),blk,0,stream>>>(Qph, Qpl, KPh, KPl, Vt, P2h, P2l);
  gemm_mfma<128,9,0,0,2><<<g2m,blk,0,stream>>>(P2h,USN, w.o_h,w.o_l, USN,USN,
      p.o_b,nullptr, XB2, CV2, USN,USN, DD,DD,DD);
  rms_h_k<<<RR2/4,blk,0,stream>>>(CV2, p.rn1_c, NPh);
  gemm_mfma<128,1,1,5,1><<<gdual,blk,0,stream>>>(NPh,USN, w.up1a_h,USN,
      w.up1b_h,USN, p.mlp1_up_b, p.mlp1_up_b+EE, nullptr, nullptr,
      ACTh, USN, DD,DD,EE);
  gemm_mfma<128,9,0,0,2><<<g2m,blk,0,stream>>>(ACTh,USN, w.dn1_h,w.dn1_l, USN,USN,
      p.mlp1_dn_b,nullptr, CV2, OUT2, USN,USN, EE,EE,DD);

  // ---- combine ----
  comb_k<<<RR*DD/256, blk, 0, stream>>>(OUT2, OUT2 + RD, Z, skip, (float*)d_out);
}

// Round 6
// 710.495 us; speedup vs baseline: 1.3005x; 1.3005x over previous
//
#include <hip/hip_runtime.h>
#include <math.h>
#include <stddef.h>

// ---------------------------------------------------------------------------
// BiDiGemma forward. Round 15: R13 + rms_h_k only.
// R14's BN=128 dual-up REVERTED: VGPR 148 / occupancy 11% collapse made each
// instance 2x slower (64.6 -> 126.6us). BN=64 dual-up restored (occ 27%).
// Kept: gates_conv fusion, kv-merge (OUT=7), scan3 hi-only, rms_h_k x3.
// ---------------------------------------------------------------------------

#define BB   4
#define SS   4096
#define DD   256
#define HH   4
#define HDIM 64
#define EE   768
#define RR   (BB*SS)        // rows per branch
#define RR2  (2*RR)         // merged rows
#define WNN  256
#define CH   64
#define NCH  (SS/CH)

typedef __attribute__((ext_vector_type(8))) short bfrag;
typedef __attribute__((ext_vector_type(4))) float f4acc;

__device__ __forceinline__ float geluf(float x){
  float u = 1.5957691216f*(x + 0.044715f*x*x*x);
  float e = __expf(u);
  float t = 1.f - 2.f/(e+1.f);
  return 0.5f*x*(1.f+t);
}
__device__ __forceinline__ float sigm(float x){ return 1.0f/(1.0f+expf(-x)); }

__device__ __forceinline__ unsigned short f2bf(float x){
  unsigned u = __float_as_uint(x);
  return (unsigned short)((u + 0x7FFFu + ((u>>16)&1u)) >> 16);
}
__device__ __forceinline__ float bf2f(unsigned short h){
  return __uint_as_float(((unsigned)h) << 16);
}
__device__ __forceinline__ void split2(float v, unsigned short* h, unsigned short* l){
  unsigned short hb = f2bf(v);
  *h = hb; *l = f2bf(v - bf2f(hb));
}

__device__ __forceinline__ float wredSum(float v){
#pragma unroll
  for(int o=32;o>0;o>>=1) v += __shfl_xor(v,o,64);
  return v;
}

// ---------------------------------------------------------------------------
__global__ __launch_bounds__(256) void ln_z_k(const float* __restrict__ skip,
    const float* __restrict__ g, const float* __restrict__ b,
    unsigned short* __restrict__ oh, unsigned short* __restrict__ ol,
    float* __restrict__ z)
{
  int row  = blockIdx.x*4 + (threadIdx.x>>6);
  int lane = threadIdx.x & 63;
  float4 v = ((const float4*)(skip + (size_t)row*DD))[lane];
  float s  = v.x+v.y+v.z+v.w;
  float sq = v.x*v.x+v.y*v.y+v.z*v.z+v.w*v.w;
  float si = v.x*sigm(v.x)+v.y*sigm(v.y)+v.z*sigm(v.z)+v.w*sigm(v.w);
  s = wredSum(s); sq = wredSum(sq); si = wredSum(si);
  float mean = s*(1.0f/DD);
  float var  = sq*(1.0f/DD) - mean*mean;
  float inv  = rsqrtf(var + 1e-5f);
  float4 gv = ((const float4*)g)[lane];
  float4 bv = ((const float4*)b)[lane];
  float o0 = (v.x-mean)*inv*gv.x + bv.x;
  float o1 = (v.y-mean)*inv*gv.y + bv.y;
  float o2 = (v.z-mean)*inv*gv.z + bv.z;
  float o3 = (v.w-mean)*inv*gv.w + bv.w;
  ushort4 hi, lo;
  split2(o0,&hi.x,&lo.x); split2(o1,&hi.y,&lo.y);
  split2(o2,&hi.z,&lo.z); split2(o3,&hi.w,&lo.w);
  ((ushort4*)(oh + (size_t)row*DD))[lane] = hi;
  ((ushort4*)(ol + (size_t)row*DD))[lane] = lo;
  if(lane==0) z[row] = sigm(si*(1.0f/DD));
}

__global__ __launch_bounds__(256) void rms_k(const float* __restrict__ x,
    const float* __restrict__ t,
    unsigned short* __restrict__ oh, unsigned short* __restrict__ ol)
{
  int row  = blockIdx.x*4 + (threadIdx.x>>6);
  int lane = threadIdx.x & 63;
  float4 v = ((const float4*)(x + (size_t)row*DD))[lane];
  float sq = v.x*v.x+v.y*v.y+v.z*v.z+v.w*v.w;
  sq = wredSum(sq);
  float inv = rsqrtf(sq*(1.0f/DD) + 1e-6f);
  float4 tv = ((const float4*)t)[lane];
  float o0 = v.x*inv*(1.0f+tv.x);
  float o1 = v.y*inv*(1.0f+tv.y);
  float o2 = v.z*inv*(1.0f+tv.z);
  float o3 = v.w*inv*(1.0f+tv.w);
  ushort4 hi, lo;
  split2(o0,&hi.x,&lo.x); split2(o1,&hi.y,&lo.y);
  split2(o2,&hi.z,&lo.z); split2(o3,&hi.w,&lo.w);
  ((ushort4*)(oh + (size_t)row*DD))[lane] = hi;
  ((ushort4*)(ol + (size_t)row*DD))[lane] = lo;
}

// hi-plane-only rms (consumers are A-hi-only GEMMs)
__global__ __launch_bounds__(256) void rms_h_k(const float* __restrict__ x,
    const float* __restrict__ t,
    unsigned short* __restrict__ oh)
{
  int row  = blockIdx.x*4 + (threadIdx.x>>6);
  int lane = threadIdx.x & 63;
  float4 v = ((const float4*)(x + (size_t)row*DD))[lane];
  float sq = v.x*v.x+v.y*v.y+v.z*v.z+v.w*v.w;
  sq = wredSum(sq);
  float inv = rsqrtf(sq*(1.0f/DD) + 1e-6f);
  float4 tv = ((const float4*)t)[lane];
  ushort4 hi;
  hi.x = f2bf(v.x*inv*(1.0f+tv.x));
  hi.y = f2bf(v.y*inv*(1.0f+tv.y));
  hi.z = f2bf(v.z*inv*(1.0f+tv.z));
  hi.w = f2bf(v.w*inv*(1.0f+tv.w));
  ((ushort4*)(oh + (size_t)row*DD))[lane] = hi;
}

// ---------------------------------------------------------------------------
struct TS  { const float* s; unsigned short* h; unsigned short* l; int K; int N; };
struct TS8 { TS t[8]; };

__global__ __launch_bounds__(256) void tsplit8_k(TS8 g){
  TS tt = g.t[blockIdx.y];
  int idx = blockIdx.x*256 + threadIdx.x;
  int tot = tt.K*tt.N;
  if(idx >= tot) return;
  int k = idx / tt.N;
  int n = idx - k*tt.N;
  float x = tt.s[idx];
  unsigned short hb = f2bf(x);
  unsigned short lb = f2bf(x - bf2f(hb));
  tt.h[(size_t)n*tt.K + k] = hb;
  tt.l[(size_t)n*tt.K + k] = lb;
}

// ---------------------------------------------------------------------------
// Split-bf16 MFMA GEMM.
// TERMS: 3 = AhBh+AhBl+AlBh ; 2 = AhBh+AhBl ; 1 = AhBh (pure bf16).
// MODE bits: 1=bias0, 2=gelu, 8=+Res. DUAL: gelu(A@B0+b0)*(A@B1+b1).
// OUT: 0 fp32; 1 hi/lo planes; 2 RoPE-q; 3 RoPE-k; 4 V^T bf16; 5 hi-only;
//      7 (DUAL) acc->RoPE-k planes + acc2->V^T bf16 into (ushort*)C.
// ---------------------------------------------------------------------------
template<int BN, int MODE, int DUAL, int OUT, int TERMS>
__global__ __launch_bounds__(256) void gemm_mfma(
    const unsigned short* __restrict__ Ah_g, const unsigned short* __restrict__ Al_g,
    const unsigned short* __restrict__ B0h, const unsigned short* __restrict__ B0l,
    const unsigned short* __restrict__ B1h, const unsigned short* __restrict__ B1l,
    const float* __restrict__ bias0, const float* __restrict__ bias1,
    const float* __restrict__ Res, float* __restrict__ C,
    unsigned short* __restrict__ Ch, unsigned short* __restrict__ Cl,
    int K, int lda, int ldc)
{
  constexpr int NT = BN/32;
  constexpr int ST = 40;
  __shared__ unsigned short Ash[128*ST];
  __shared__ unsigned short Asl[TERMS==3 ? 128*ST : 8];
  __shared__ unsigned short Bsh[BN*ST];
  __shared__ unsigned short Bsl[TERMS>=2 ? BN*ST : 8];
  __shared__ unsigned short B2h[DUAL?BN*ST:8];
  __shared__ unsigned short B2l[(DUAL && TERMS>=2)?BN*ST:8];

  const int tid  = threadIdx.x;
  const int lane = tid & 63, wave = tid >> 6;
  const int wm = wave >> 1, wn = wave & 1;
  const int bm = blockIdx.y*128, bn = blockIdx.x*BN;
  const int m16 = lane & 15, q = lane >> 4;

  f4acc acc[4][NT];
  f4acc acc2[DUAL?4:1][DUAL?NT:1];
#pragma unroll
  for(int i=0;i<4;i++)
#pragma unroll
    for(int j=0;j<NT;j++){
      acc[i][j] = (f4acc)0.f;
      if constexpr(DUAL) acc2[i][j] = (f4acc)0.f;
    }

  // staging map: 4 lanes per row; r0 in [0,64), chunk c0 in [0,4)
  const int r0 = tid >> 2, c0 = tid & 3;
  const int coff = c0*8;
  const int d0 = r0*ST + coff, d1 = (r0+64)*ST + coff;

  const unsigned short* pAh0 = Ah_g + (size_t)(bm+r0)*lda + coff;
  const unsigned short* pAh1 = pAh0 + (size_t)64*lda;
  const unsigned short* pAl0 = (TERMS==3) ? (Al_g + (size_t)(bm+r0)*lda + coff)
                                          : (const unsigned short*)nullptr;
  const unsigned short* pAl1 = (TERMS==3) ? (pAl0 + (size_t)64*lda)
                                          : (const unsigned short*)nullptr;
  const unsigned short *pB0h0=nullptr,*pB0h1=nullptr,*pB0l0=nullptr,*pB0l1=nullptr;
  const unsigned short *pBa=nullptr,*pBb=nullptr,*pBc=nullptr,*pBd=nullptr;
  if constexpr(BN==128){
    pB0h0 = B0h + (size_t)(bn+r0)*K + coff;  pB0h1 = pB0h0 + (size_t)64*K;
    if constexpr(TERMS>=2){
      pB0l0 = B0l + (size_t)(bn+r0)*K + coff;  pB0l1 = pB0l0 + (size_t)64*K;
    }
  } else {
    pBa = B0h + (size_t)(bn+r0)*K + coff;
    if constexpr(TERMS>=2) pBb = B0l + (size_t)(bn+r0)*K + coff;
    if constexpr(DUAL){
      pBc = B1h + (size_t)(bn+r0)*K + coff;
      if constexpr(TERMS>=2) pBd = B1l + (size_t)(bn+r0)*K + coff;
    }
  }

  for(int k0 = 0; k0 < K; k0 += 32){
    // ---- A stage ----
    *(float4*)&Ash[d0] = *(const float4*)(pAh0 + k0);
    *(float4*)&Ash[d1] = *(const float4*)(pAh1 + k0);
    if constexpr(TERMS==3){
      *(float4*)&Asl[d0] = *(const float4*)(pAl0 + k0);
      *(float4*)&Asl[d1] = *(const float4*)(pAl1 + k0);
    }
    // ---- B stage ----
    if constexpr(BN==128){
      *(float4*)&Bsh[d0] = *(const float4*)(pB0h0 + k0);
      *(float4*)&Bsh[d1] = *(const float4*)(pB0h1 + k0);
      if constexpr(TERMS>=2){
        *(float4*)&Bsl[d0] = *(const float4*)(pB0l0 + k0);
        *(float4*)&Bsl[d1] = *(const float4*)(pB0l1 + k0);
      }
    } else {
      *(float4*)&Bsh[d0] = *(const float4*)(pBa + k0);
      if constexpr(TERMS>=2) *(float4*)&Bsl[d0] = *(const float4*)(pBb + k0);
      if constexpr(DUAL){
        *(float4*)&B2h[d0] = *(const float4*)(pBc + k0);
        if constexpr(TERMS>=2) *(float4*)&B2l[d0] = *(const float4*)(pBd + k0);
      }
    }
    __syncthreads();

    bfrag ah[4], al[TERMS==3?4:1], b0hf[NT], b0lf[TERMS>=2?NT:1];
    bfrag b1hf[DUAL?NT:1], b1lf[(DUAL&&TERMS>=2)?NT:1];
#pragma unroll
    for(int mi=0;mi<4;mi++){
      int row = wm*64 + mi*16 + m16;
      ah[mi] = *(const bfrag*)&Ash[row*ST + q*8];
      if constexpr(TERMS==3) al[mi] = *(const bfrag*)&Asl[row*ST + q*8];
    }
#pragma unroll
    for(int ni=0;ni<NT;ni++){
      int n = wn*(BN/2) + ni*16 + m16;
      b0hf[ni] = *(const bfrag*)&Bsh[n*ST + q*8];
      if constexpr(TERMS>=2) b0lf[ni] = *(const bfrag*)&Bsl[n*ST + q*8];
      if constexpr(DUAL){
        b1hf[ni] = *(const bfrag*)&B2h[n*ST + q*8];
        if constexpr(TERMS>=2) b1lf[ni] = *(const bfrag*)&B2l[n*ST + q*8];
      }
    }
#pragma unroll
    for(int mi=0;mi<4;mi++)
#pragma unroll
      for(int ni=0;ni<NT;ni++){
        acc[mi][ni] = __builtin_amdgcn_mfma_f32_16x16x32_bf16(ah[mi], b0hf[ni], acc[mi][ni],0,0,0);
        if constexpr(TERMS>=2)
          acc[mi][ni] = __builtin_amdgcn_mfma_f32_16x16x32_bf16(ah[mi], b0lf[ni], acc[mi][ni],0,0,0);
        if constexpr(TERMS==3)
          acc[mi][ni] = __builtin_amdgcn_mfma_f32_16x16x32_bf16(al[mi], b0hf[ni], acc[mi][ni],0,0,0);
        if constexpr(DUAL){
          acc2[mi][ni] = __builtin_amdgcn_mfma_f32_16x16x32_bf16(ah[mi], b1hf[ni], acc2[mi][ni],0,0,0);
          if constexpr(TERMS>=2)
            acc2[mi][ni] = __builtin_amdgcn_mfma_f32_16x16x32_bf16(ah[mi], b1lf[ni], acc2[mi][ni],0,0,0);
          if constexpr(TERMS==3)
            acc2[mi][ni] = __builtin_amdgcn_mfma_f32_16x16x32_bf16(al[mi], b1hf[ni], acc2[mi][ni],0,0,0);
        }
      }
    __syncthreads();
  }

  // ---- epilogue ----
  if constexpr(OUT==0 || OUT==1 || OUT==5){
#pragma unroll
    for(int ni=0;ni<NT;ni++){
      const int col = bn + wn*(BN/2) + ni*16 + m16;
      float bv0 = (MODE&1) ? bias0[col] : 0.f;
      float bv1 = DUAL ? bias1[col] : 0.f;
#pragma unroll
      for(int mi=0;mi<4;mi++){
#pragma unroll
        for(int r=0;r<4;r++){
          const int row = bm + wm*64 + mi*16 + q*4 + r;
          float v = acc[mi][ni][r] + bv0;
          if constexpr(DUAL){
            float v2 = acc2[mi][ni][r] + bv1;
            v = geluf(v) * v2;
          } else if(MODE&2){
            v = geluf(v);
          }
          if(MODE&8) v += Res[(size_t)row*ldc + col];
          if constexpr(OUT==0){
            C[(size_t)row*ldc + col] = v;
          } else if constexpr(OUT==1){
            unsigned short hb = f2bf(v);
            Ch[(size_t)row*ldc + col] = hb;
            Cl[(size_t)row*ldc + col] = f2bf(v - bf2f(hb));
          } else {
            Ch[(size_t)row*ldc + col] = f2bf(v);
          }
        }
      }
    }
  } else if constexpr(OUT==2){
    const int hb = bn + wn*64;
    const float p = (float)m16;
    const float invf = __expf(-p * 0.575646273248511f);
#pragma unroll
    for(int mi=0;mi<4;mi++){
#pragma unroll
      for(int r=0;r<4;r++){
        const int row = bm + wm*64 + mi*16 + q*4 + r;
        const int s = row & (SS-1);
        float t = (float)s * invf;
        float sn, cs; __sincosf(t, &sn, &cs);
        float x1 = acc[mi][0][r], x2 = acc[mi][1][r];
        float v0 = (x1*cs - x2*sn)*0.125f;
        float v1 = (x2*cs + x1*sn)*0.125f;
        float v2 = acc[mi][2][r]*0.125f;
        float v3 = acc[mi][3][r]*0.125f;
        size_t base = (size_t)row*ldc + hb;
        unsigned short hh;
        hh=f2bf(v0); Ch[base+m16]=hh;    Cl[base+m16]   =f2bf(v0-bf2f(hh));
        hh=f2bf(v1); Ch[base+16+m16]=hh; Cl[base+16+m16]=f2bf(v1-bf2f(hh));
        hh=f2bf(v2); Ch[base+32+m16]=hh; Cl[base+32+m16]=f2bf(v2-bf2f(hh));
        hh=f2bf(v3); Ch[base+48+m16]=hh; Cl[base+48+m16]=f2bf(v3-bf2f(hh));
      }
    }
  } else if constexpr(OUT==3){
    const float p = (float)m16;
    const float invf = __expf(-p * 0.575646273248511f);
#pragma unroll
    for(int mi=0;mi<4;mi++){
#pragma unroll
      for(int r=0;r<4;r++){
        const int row = bm + wm*64 + mi*16 + q*4 + r;
        const int s = row & (SS-1);
        float v0, v1;
        if(wn==0){
          float t = (float)s * invf;
          float sn, cs; __sincosf(t, &sn, &cs);
          float x1 = acc[mi][0][r], x2 = acc[mi][1][r];
          v0 = x1*cs - x2*sn;
          v1 = x2*cs + x1*sn;
        } else {
          v0 = acc[mi][0][r]; v1 = acc[mi][1][r];
        }
        size_t base = (size_t)row*ldc + wn*32;
        unsigned short hh;
        hh=f2bf(v0); Ch[base+m16]=hh;    Cl[base+m16]   =f2bf(v0-bf2f(hh));
        hh=f2bf(v1); Ch[base+16+m16]=hh; Cl[base+16+m16]=f2bf(v1-bf2f(hh));
      }
    }
  } else if constexpr(OUT==4){
#pragma unroll
    for(int ni=0;ni<NT;ni++){
      const int col = wn*32 + ni*16 + m16;
#pragma unroll
      for(int mi=0;mi<4;mi++){
        const int rowb = bm + wm*64 + mi*16 + q*4;
        const int b = rowb >> 12, sl = rowb & (SS-1);
        ushort4 hv;
        hv.x = f2bf(acc[mi][ni][0]); hv.y = f2bf(acc[mi][ni][1]);
        hv.z = f2bf(acc[mi][ni][2]); hv.w = f2bf(acc[mi][ni][3]);
        *(ushort4*)(Ch + ((size_t)(b*64 + col))*SS + sl) = hv;
      }
    }
  } else if constexpr(OUT==7){
    // acc -> RoPE-k hi/lo planes (ldc=HDIM); acc2 -> V^T bf16 into (ushort*)C
    const float p = (float)m16;
    const float invf = __expf(-p * 0.575646273248511f);
#pragma unroll
    for(int mi=0;mi<4;mi++){
#pragma unroll
      for(int r=0;r<4;r++){
        const int row = bm + wm*64 + mi*16 + q*4 + r;
        const int s = row & (SS-1);
        float v0, v1;
        if(wn==0){
          float t = (float)s * invf;
          float sn, cs; __sincosf(t, &sn, &cs);
          float x1 = acc[mi][0][r], x2 = acc[mi][1][r];
          v0 = x1*cs - x2*sn;
          v1 = x2*cs + x1*sn;
        } else {
          v0 = acc[mi][0][r]; v1 = acc[mi][1][r];
        }
        size_t base = (size_t)row*ldc + wn*32;
        unsigned short hh;
        hh=f2bf(v0); Ch[base+m16]=hh;    Cl[base+m16]   =f2bf(v0-bf2f(hh));
        hh=f2bf(v1); Ch[base+16+m16]=hh; Cl[base+16+m16]=f2bf(v1-bf2f(hh));
      }
    }
    if constexpr(DUAL){
      unsigned short* Cv = (unsigned short*)C;
#pragma unroll
      for(int ni=0;ni<NT;ni++){
        const int col = wn*32 + ni*16 + m16;
#pragma unroll
        for(int mi=0;mi<4;mi++){
          const int rowb = bm + wm*64 + mi*16 + q*4;
          const int b = rowb >> 12, sl = rowb & (SS-1);
          ushort4 hv;
          hv.x = f2bf(acc2[mi][ni][0]); hv.y = f2bf(acc2[mi][ni][1]);
          hv.z = f2bf(acc2[mi][ni][2]); hv.w = f2bf(acc2[mi][ni][3]);
          *(ushort4*)(Cv + ((size_t)(b*64 + col))*SS + sl) = hv;
        }
      }
    }
  }
}

// ---------------------------------------------------------------------------
// Fused conv + RG-LRU gate path on MFMA. Per block: one head, 128 rows.
// ---------------------------------------------------------------------------
__global__ __launch_bounds__(256) void gates_conv_k(
    const float* __restrict__ X,      // lx output [RR2][DD] (pre-conv)
    const float* __restrict__ cw, const float* __restrict__ cb,
    const unsigned short* __restrict__ igth, const unsigned short* __restrict__ igtl,
    const unsigned short* __restrict__ agth, const unsigned short* __restrict__ agtl,
    const float* __restrict__ igb, const float* __restrict__ agb,
    const float* __restrict__ ap,
    float* __restrict__ Aout, float* __restrict__ Bout)
{
  constexpr int ST = 72;
  __shared__ unsigned short Ash[128*ST];
  __shared__ unsigned short Asl[128*ST];

  const int h  = blockIdx.x;          // head
  const int bm = blockIdx.y*128;
  const int tid = threadIdx.x;
  const int lane = tid & 63, wave = tid >> 6;
  const int wm = wave >> 1, wn = wave & 1;
  const int m16 = lane & 15, q = lane >> 4;

  // ---- conv + split stage: 16 strips x 8 rows, 16 col-groups x 4 cols ----
  {
    const int strip = tid >> 4;
    const int cg = (tid & 15)*4;
    const int col0 = h*HDIM + cg;
    const int r0 = bm + strip*8;
    float h0[4], h1[4], h2[4];
#pragma unroll
    for(int i=0;i<3;i++){
      int rr = r0 - 3 + i;
      int rc = rr < 0 ? 0 : rr;
      float4 hv = *(const float4*)(X + (size_t)rc*DD + col0);
      float* dst = (i==0)?h0:((i==1)?h1:h2);
      dst[0]=hv.x; dst[1]=hv.y; dst[2]=hv.z; dst[3]=hv.w;
    }
    float4 w0v = *(const float4*)(cw + 0*DD + col0);
    float4 w1v = *(const float4*)(cw + 1*DD + col0);
    float4 w2v = *(const float4*)(cw + 2*DD + col0);
    float4 w3v = *(const float4*)(cw + 3*DD + col0);
    float4 bbv = *(const float4*)(cb + col0);
    const float* w0 = (const float*)&w0v; const float* w1 = (const float*)&w1v;
    const float* w2 = (const float*)&w2v; const float* w3 = (const float*)&w3v;
    const float* bb = (const float*)&bbv;
    for(int rr=0; rr<8; rr++){
      const int r = r0 + rr;
      const int s = r & (SS-1);
      float4 cv = *(const float4*)(X + (size_t)r*DD + col0);
      float cur[4]; cur[0]=cv.x; cur[1]=cv.y; cur[2]=cv.z; cur[3]=cv.w;
      ushort4 hi, lo;
      unsigned short* hp = (unsigned short*)&hi;
      unsigned short* lp = (unsigned short*)&lo;
#pragma unroll
      for(int j=0;j<4;j++){
        float acc = bb[j] + w3[j]*cur[j];
        if(s>=1) acc += w2[j]*h2[j];
        if(s>=2) acc += w1[j]*h1[j];
        if(s>=3) acc += w0[j]*h0[j];
        unsigned short hb = f2bf(acc);
        hp[j] = hb; lp[j] = f2bf(acc - bf2f(hb));
      }
      const int dst = (strip*8+rr)*ST + cg;
      *(ushort4*)&Ash[dst] = hi;
      *(ushort4*)&Asl[dst] = lo;
#pragma unroll
      for(int j=0;j<4;j++){ h0[j]=h1[j]; h1[j]=h2[j]; h2[j]=cur[j]; }
    }
  }
  __syncthreads();

  f4acc accI[4][2], accA[4][2];
#pragma unroll
  for(int i=0;i<4;i++)
#pragma unroll
    for(int j=0;j<2;j++){ accI[i][j]=(f4acc)0.f; accA[i][j]=(f4acc)0.f; }

  const size_t wbase = (size_t)h*HDIM*HDIM;
#pragma unroll
  for(int ks=0;ks<2;ks++){
    bfrag ah[4], al[4];
#pragma unroll
    for(int mi=0;mi<4;mi++){
      const int row = wm*64 + mi*16 + m16;
      ah[mi] = *(const bfrag*)&Ash[row*ST + ks*32 + q*8];
      al[mi] = *(const bfrag*)&Asl[row*ST + ks*32 + q*8];
    }
#pragma unroll
    for(int ni=0;ni<2;ni++){
      const size_t bo = wbase + (size_t)(wn*32 + ni*16 + m16)*HDIM + ks*32 + q*8;
      bfrag bIh = *(const bfrag*)(igth + bo);
      bfrag bIl = *(const bfrag*)(igtl + bo);
      bfrag bAh = *(const bfrag*)(agth + bo);
      bfrag bAl = *(const bfrag*)(agtl + bo);
#pragma unroll
      for(int mi=0;mi<4;mi++){
        accI[mi][ni] = __builtin_amdgcn_mfma_f32_16x16x32_bf16(ah[mi], bIh, accI[mi][ni],0,0,0);
        accI[mi][ni] = __builtin_amdgcn_mfma_f32_16x16x32_bf16(ah[mi], bIl, accI[mi][ni],0,0,0);
        accI[mi][ni] = __builtin_amdgcn_mfma_f32_16x16x32_bf16(al[mi], bIh, accI[mi][ni],0,0,0);
        accA[mi][ni] = __builtin_amdgcn_mfma_f32_16x16x32_bf16(ah[mi], bAh, accA[mi][ni],0,0,0);
        accA[mi][ni] = __builtin_amdgcn_mfma_f32_16x16x32_bf16(ah[mi], bAl, accA[mi][ni],0,0,0);
        accA[mi][ni] = __builtin_amdgcn_mfma_f32_16x16x32_bf16(al[mi], bAh, accA[mi][ni],0,0,0);
      }
    }
  }

  // ---- gate epilogue ----
#pragma unroll
  for(int ni=0;ni<2;ni++){
    const int cl  = wn*32 + ni*16 + m16;     // col within head
    const int col = h*HDIM + cl;
    const float bI = igb[col], bA = agb[col];
    const float apv = ap[col];
    const float sp = (apv > 20.f) ? apv : log1pf(expf(apv));
#pragma unroll
    for(int mi=0;mi<4;mi++){
#pragma unroll
      for(int r=0;r<4;r++){
        const int lrow = wm*64 + mi*16 + q*4 + r;
        const int row = bm + lrow;
        const int s = row & (SS-1);
        float gx = 1.f/(1.f + __expf(-(accI[mi][ni][r] + bI)));
        float ga = 1.f/(1.f + __expf(-(accA[mi][ni][r] + bA)));
        float la = -8.f * ga * sp;
        float a_ = __expf(la);
        float mult = (s==0) ? 1.f : sqrtf(fmaxf(1.f - __expf(2.f*la), 0.f));
        float x = bf2f(Ash[lrow*ST + cl]) + bf2f(Asl[lrow*ST + cl]);
        Aout[(size_t)row*DD + col] = a_;
        Bout[(size_t)row*DD + col] = x * gx * mult;
      }
    }
  }
}

__global__ __launch_bounds__(256) void scan1_k(const float* __restrict__ A,
    const float* __restrict__ Bv, float* __restrict__ csa, float* __restrict__ csb)
{
  int idx = blockIdx.x*256 + threadIdx.x;
  int d = idx & (DD-1);
  int c = (idx >> 8) & (NCH-1);
  int b = idx >> 14;
  size_t base = ((size_t)b*SS + (size_t)c*CH)*DD + d;
  float Aa = 1.f, Bb_ = 0.f;
  for(int t=0;t<CH;t++){
    float a  = A [base + (size_t)t*DD];
    float bb = Bv[base + (size_t)t*DD];
    Aa  = a*Aa;
    Bb_ = a*Bb_ + bb;
  }
  csa[idx] = Aa; csb[idx] = Bb_;
}

__global__ __launch_bounds__(256) void scan2_k(const float* __restrict__ csa,
    float* __restrict__ csb)
{
  int idx = blockIdx.x*256 + threadIdx.x;
  int d = idx & (DD-1);
  int b = idx >> 8;
  float h = 0.f;
  for(int c=0;c<NCH;c++){
    size_t i = ((size_t)b*NCH + c)*DD + d;
    float Aa = csa[i], Bb_ = csb[i];
    csb[i] = h;
    h = Aa*h + Bb_;
  }
}

__global__ __launch_bounds__(256) void scan3_k(const float* __restrict__ A,
    const float* __restrict__ Bv, const float* __restrict__ csb,
    const unsigned short* __restrict__ Yh,
    unsigned short* __restrict__ Hh)
{
  int idx = blockIdx.x*256 + threadIdx.x;
  int d = idx & (DD-1);
  int c = (idx >> 8) & (NCH-1);
  int b = idx >> 14;
  size_t base = ((size_t)b*SS + (size_t)c*CH)*DD + d;
  float h = csb[idx];
  for(int t=0;t<CH;t++){
    float a  = A [base + (size_t)t*DD];
    float bb = Bv[base + (size_t)t*DD];
    h = a*h + bb;
    float v = h * bf2f(Yh[base + (size_t)t*DD]);
    Hh[base + (size_t)t*DD] = f2bf(v);
  }
}

// ---------------------------------------------------------------------------
#define AST 72
__global__ __launch_bounds__(256) void attn_k(
    const unsigned short* __restrict__ Qh, const unsigned short* __restrict__ Ql,
    const unsigned short* __restrict__ Kh, const unsigned short* __restrict__ Kl,
    const unsigned short* __restrict__ Vt,
    unsigned short* __restrict__ Oh, unsigned short* __restrict__ Ol)
{
  __shared__ unsigned short Ksh[64*AST], Ksl[64*AST], Vsh[64*AST];
  __shared__ unsigned short Ps[4*16*AST];

  const int qt = blockIdx.x & 3, n = blockIdx.x >> 2;
  const int h = blockIdx.y, b = blockIdx.z;
  const int tid = threadIdx.x;
  const int lane = tid & 63, w = tid >> 6;
  const int m16 = lane & 15, q = lane >> 4;
  const int s0 = n*WNN + qt*64;

  const size_t qro = ((size_t)(b*SS + s0 + w*16 + m16))*DD + h*HDIM + q*8;
  bfrag qh0 = *(const bfrag*)(Qh + qro);
  bfrag qh1 = *(const bfrag*)(Qh + qro + 32);
  bfrag ql0 = *(const bfrag*)(Ql + qro);
  bfrag ql1 = *(const bfrag*)(Ql + qro + 32);

  float mrow[4], lrow[4];
  f4acc oacc[4];
#pragma unroll
  for(int i=0;i<4;i++){ mrow[i]=-3.0e38f; lrow[i]=0.f; oacc[i]=(f4acc)0.f; }

  const int ktlo = (n==0) ? 4 : qt;
  const int kthi = qt + 4;
  const int sr = tid >> 2, sc = tid & 3;

  for(int kt=ktlo; kt<=kthi; kt++){
    const int kbase = (n-1)*WNN + kt*64;
#pragma unroll
    for(int cc=0; cc<2; cc++){
      int g = sc + cc*4;
      *(float4*)&Ksh[sr*AST + g*8] =
        *(const float4*)(Kh + (size_t)(b*SS + kbase + sr)*HDIM + g*8);
      *(float4*)&Ksl[sr*AST + g*8] =
        *(const float4*)(Kl + (size_t)(b*SS + kbase + sr)*HDIM + g*8);
      *(float4*)&Vsh[sr*AST + g*8] =
        *(const float4*)(Vt + ((size_t)(b*64 + sr))*SS + kbase + g*8);
    }
    __syncthreads();

    f4acc sacc[4];
#pragma unroll
    for(int nt=0;nt<4;nt++) sacc[nt] = (f4acc)0.f;
#pragma unroll
    for(int nt=0;nt<4;nt++){
      const int kr = (nt*16+m16)*AST;
      bfrag kh0 = *(const bfrag*)&Ksh[kr + q*8];
      bfrag kh1 = *(const bfrag*)&Ksh[kr + 32 + q*8];
      bfrag kl0 = *(const bfrag*)&Ksl[kr + q*8];
      bfrag kl1 = *(const bfrag*)&Ksl[kr + 32 + q*8];
      sacc[nt] = __builtin_amdgcn_mfma_f32_16x16x32_bf16(qh0, kh0, sacc[nt],0,0,0);
      sacc[nt] = __builtin_amdgcn_mfma_f32_16x16x32_bf16(qh0, kl0, sacc[nt],0,0,0);
      sacc[nt] = __builtin_amdgcn_mfma_f32_16x16x32_bf16(ql0, kh0, sacc[nt],0,0,0);
      sacc[nt] = __builtin_amdgcn_mfma_f32_16x16x32_bf16(qh1, kh1, sacc[nt],0,0,0);
      sacc[nt] = __builtin_amdgcn_mfma_f32_16x16x32_bf16(qh1, kl1, sacc[nt],0,0,0);
      sacc[nt] = __builtin_amdgcn_mfma_f32_16x16x32_bf16(ql1, kh1, sacc[nt],0,0,0);
    }

    const bool needlo = (kt == qt+4);
    const bool needhi = (kt == qt);
#pragma unroll
    for(int r=0;r<4;r++){
      int qp = qt*64 + w*16 + q*4 + r;
      float sv[4];
      float tm = -3.0e38f;
#pragma unroll
      for(int nt=0;nt<4;nt++){
        float scv = sacc[nt][r];
        if(needlo || needhi){
          int kj = kt*64 + nt*16 + m16;
          int diff = qp + WNN - kj;
          bool ok = (!needlo || diff >= 0) && (!needhi || diff <= WNN);
          scv = ok ? scv : -3.0e38f;
        }
        sv[nt] = scv;
        tm = fmaxf(tm, scv);
      }
#pragma unroll
      for(int off=1; off<16; off<<=1) tm = fmaxf(tm, __shfl_xor(tm, off, 64));
      float mn = fmaxf(mrow[r], tm);
      float alpha = __expf(mrow[r]-mn);
      float rs = 0.f;
#pragma unroll
      for(int nt=0;nt<4;nt++){
        float pp = __expf(sv[nt]-mn);
        rs += pp;
        Ps[w*16*AST + (q*4+r)*AST + nt*16 + m16] = f2bf(pp);
      }
#pragma unroll
      for(int off=1; off<16; off<<=1) rs += __shfl_xor(rs, off, 64);
      lrow[r] = lrow[r]*alpha + rs;
      mrow[r] = mn;
#pragma unroll
      for(int nt=0;nt<4;nt++) oacc[nt][r] *= alpha;
    }

#pragma unroll
    for(int s=0;s<2;s++){
      bfrag pa = *(const bfrag*)&Ps[w*16*AST + m16*AST + s*32 + q*8];
#pragma unroll
      for(int nt=0;nt<4;nt++){
        bfrag vh_ = *(const bfrag*)&Vsh[(nt*16+m16)*AST + s*32 + q*8];
        oacc[nt] = __builtin_amdgcn_mfma_f32_16x16x32_bf16(pa, vh_, oacc[nt],0,0,0);
      }
    }
    __syncthreads();
  }

#pragma unroll
  for(int r=0;r<4;r++){
    float invl = 1.f/lrow[r];
    const size_t rowbase = ((size_t)(b*SS + s0 + w*16 + q*4 + r))*DD + h*HDIM;
#pragma unroll
    for(int nt=0;nt<4;nt++){
      float v = oacc[nt][r]*invl;
      unsigned short hb = f2bf(v);
      Oh[rowbase + nt*16 + m16] = hb;
      Ol[rowbase + nt*16 + m16] = f2bf(v - bf2f(hb));
    }
  }
}

__global__ __launch_bounds__(256) void comb_k(const float* __restrict__ of,
    const float* __restrict__ ob, const float* __restrict__ z,
    const float* __restrict__ skip, float* __restrict__ out)
{
  int idx = blockIdx.x*256 + threadIdx.x;
  int r = idx >> 8;
  out[idx] = z[r]*(of[idx]+ob[idx]) + skip[idx];
}

// ---------------------------------------------------------------------------
struct Params {
  const float *ln_gamma,*ln_beta,*proj_w,*proj_b,*fconv_w,*fconv_b,*bconv_w,*bconv_b,
    *rn0_t,*rn0_c,*ly_w,*ly_b,*lx_w,*lx_b,*lo_w,*lo_b,*c1d_w,*c1d_b,*a_param,
    *ig_w,*ig_b,*ag_w,*ag_b,*mlp0_up_w,*mlp0_up_b,*mlp0_dn_w,*mlp0_dn_b,
    *rn1_t,*rn1_c,*q_w,*k_w,*v_w,*o_w,*o_b,*mlp1_up_w,*mlp1_up_b,*mlp1_dn_w,*mlp1_dn_b;
};

struct WSplit {
  unsigned short *proj_h,*proj_l,*fconv_h,*fconv_l,*bconv_h,*bconv_l,
    *ly_h,*ly_l,*lx_h,*lx_l,*lo_h,*lo_l,*q_h,*q_l,*o_h,*o_l,
    *k_h,*k_l,*v_h,*v_l,
    *up0a_h,*up0a_l,*up0b_h,*up0b_l,*up1a_h,*up1a_l,*up1b_h,*up1b_l,
    *dn0_h,*dn0_l,*dn1_h,*dn1_l,
    *igt_h,*igt_l,*agt_h,*agt_l;
};

#define USN ((unsigned short*)nullptr)

extern "C" void kernel_launch(void* const* d_in, const int* in_sizes, int n_in,
                              void* d_out, int out_size, void* d_ws, size_t ws_size,
                              hipStream_t stream)
{
  (void)in_sizes; (void)n_in; (void)out_size; (void)ws_size;
  const float* skip = (const float*)d_in[0];
  Params p;
  p.ln_gamma  =(const float*)d_in[1];  p.ln_beta  =(const float*)d_in[2];
  p.proj_w    =(const float*)d_in[3];  p.proj_b   =(const float*)d_in[4];
  p.fconv_w   =(const float*)d_in[5];  p.fconv_b  =(const float*)d_in[6];
  p.bconv_w   =(const float*)d_in[7];  p.bconv_b  =(const float*)d_in[8];
  p.rn0_t     =(const float*)d_in[9];  p.rn0_c    =(const float*)d_in[10];
  p.ly_w      =(const float*)d_in[11]; p.ly_b     =(const float*)d_in[12];
  p.lx_w      =(const float*)d_in[13]; p.lx_b     =(const float*)d_in[14];
  p.lo_w      =(const float*)d_in[15]; p.lo_b     =(const float*)d_in[16];
  p.c1d_w     =(const float*)d_in[17]; p.c1d_b    =(const float*)d_in[18];
  p.a_param   =(const float*)d_in[19];
  p.ig_w      =(const float*)d_in[20]; p.ig_b     =(const float*)d_in[21];
  p.ag_w      =(const float*)d_in[22]; p.ag_b     =(const float*)d_in[23];
  p.mlp0_up_w =(const float*)d_in[24]; p.mlp0_up_b=(const float*)d_in[25];
  p.mlp0_dn_w =(const float*)d_in[26]; p.mlp0_dn_b=(const float*)d_in[27];
  p.rn1_t     =(const float*)d_in[28]; p.rn1_c    =(const float*)d_in[29];
  p.q_w       =(const float*)d_in[30]; p.k_w      =(const float*)d_in[31];
  p.v_w       =(const float*)d_in[32]; p.o_w      =(const float*)d_in[33];
  p.o_b       =(const float*)d_in[34];
  p.mlp1_up_w =(const float*)d_in[35]; p.mlp1_up_b=(const float*)d_in[36];
  p.mlp1_dn_w =(const float*)d_in[37]; p.mlp1_dn_b=(const float*)d_in[38];

  float* ws = (float*)d_ws;
  const size_t RD  = (size_t)RR*DD;
  const size_t PD2 = (size_t)RR2*DD;
  size_t off = 0;
  float* Z   = ws + off; off += 16384;
  float* XB2 = ws + off; off += 2*RD;
  float* CV2 = ws + off; off += 2*RD;
  float* W1  = ws + off; off += 2*RD;
  float* W2  = ws + off; off += 2*RD;
  float* W3  = ws + off; off += RD;
  float* W4  = ws + off; off += 2*RD;

  float* CSA = CV2;
  float* CSB = CV2 + 8*NCH*DD;

  unsigned short* NPh = (unsigned short*)W4;  unsigned short* NPl = NPh + PD2;
  float* BT = W4;                              // bterm fp32 (gates output)
  unsigned short* HYh = (unsigned short*)W1;   // scan3 output (hi only)
  unsigned short* X0h = (unsigned short*)W1;  unsigned short* X0l = X0h + (size_t)RR*DD;
  float* XR2 = W1;
  unsigned short* Qph = (unsigned short*)W1;  unsigned short* Qpl = Qph + PD2;
  float* Abuf = W2;
  unsigned short* P2h = (unsigned short*)W2;  unsigned short* P2l = P2h + PD2;
  unsigned short* Yh  = (unsigned short*)W3;
  unsigned short* KPh = (unsigned short*)W3;  unsigned short* KPl = KPh + (size_t)RR2*HDIM;
  unsigned short* Vt  = KPl + (size_t)RR2*HDIM;
  unsigned short* ACTh = (unsigned short*)W1;
  float* OUT2 = XB2;

  unsigned short* sp = (unsigned short*)(ws + off);
  WSplit w;
  auto alloc_s = [&](size_t n){ unsigned short* r = sp; sp += n; return r; };
  const size_t SDD = (size_t)DD*DD, SKV = (size_t)DD*HDIM, SUP = (size_t)DD*EE;
  const size_t SBD = (size_t)HH*HDIM*HDIM;
  w.proj_h=alloc_s(SDD);  w.proj_l=alloc_s(SDD);
  w.fconv_h=alloc_s(SDD); w.fconv_l=alloc_s(SDD);
  w.bconv_h=alloc_s(SDD); w.bconv_l=alloc_s(SDD);
  w.ly_h=alloc_s(SDD);    w.ly_l=alloc_s(SDD);
  w.lx_h=alloc_s(SDD);    w.lx_l=alloc_s(SDD);
  w.lo_h=alloc_s(SDD);    w.lo_l=alloc_s(SDD);
  w.q_h=alloc_s(SDD);     w.q_l=alloc_s(SDD);
  w.o_h=alloc_s(SDD);     w.o_l=alloc_s(SDD);
  w.k_h=alloc_s(SKV);     w.k_l=alloc_s(SKV);
  w.v_h=alloc_s(SKV);     w.v_l=alloc_s(SKV);
  w.up0a_h=alloc_s(SUP);  w.up0a_l=alloc_s(SUP);
  w.up0b_h=alloc_s(SUP);  w.up0b_l=alloc_s(SUP);
  w.up1a_h=alloc_s(SUP);  w.up1a_l=alloc_s(SUP);
  w.up1b_h=alloc_s(SUP);  w.up1b_l=alloc_s(SUP);
  w.dn0_h=alloc_s(SUP);   w.dn0_l=alloc_s(SUP);
  w.dn1_h=alloc_s(SUP);   w.dn1_l=alloc_s(SUP);
  w.igt_h=alloc_s(SBD);   w.igt_l=alloc_s(SBD);
  w.agt_h=alloc_s(SBD);   w.agt_l=alloc_s(SBD);

  dim3 blk(256);
  dim3 g2(2,128,1);
  dim3 g2m(2,256,1), g64m(1,256,1), gdual(12,256,1);
  dim3 ggm(HH, RR2/128, 1);

  {
    TS8 ga;
    ga.t[0] = {p.proj_w,  w.proj_h,  w.proj_l,  DD, DD};
    ga.t[1] = {p.fconv_w, w.fconv_h, w.fconv_l, DD, DD};
    ga.t[2] = {p.bconv_w, w.bconv_h, w.bconv_l, DD, DD};
    ga.t[3] = {p.ly_w,    w.ly_h,    w.ly_l,    DD, DD};
    ga.t[4] = {p.lx_w,    w.lx_h,    w.lx_l,    DD, DD};
    ga.t[5] = {p.lo_w,    w.lo_h,    w.lo_l,    DD, DD};
    ga.t[6] = {p.q_w,     w.q_h,     w.q_l,     DD, DD};
    ga.t[7] = {p.o_w,     w.o_h,     w.o_l,     DD, DD};
    tsplit8_k<<<dim3(DD*DD/256, 8), blk, 0, stream>>>(ga);
    TS8 gb;
    gb.t[0] = {p.k_w,              w.k_h,    w.k_l,    DD, HDIM};
    gb.t[1] = {p.v_w,              w.v_h,    w.v_l,    DD, HDIM};
    gb.t[2] = {p.mlp0_up_w,        w.up0a_h, w.up0a_l, DD, EE};
    gb.t[3] = {p.mlp0_up_w+(size_t)DD*EE, w.up0b_h, w.up0b_l, DD, EE};
    gb.t[4] = {p.mlp1_up_w,        w.up1a_h, w.up1a_l, DD, EE};
    gb.t[5] = {p.mlp1_up_w+(size_t)DD*EE, w.up1b_h, w.up1b_l, DD, EE};
    gb.t[6] = {p.mlp0_dn_w,        w.dn0_h,  w.dn0_l,  EE, DD};
    gb.t[7] = {p.mlp1_dn_w,        w.dn1_h,  w.dn1_l,  EE, DD};
    tsplit8_k<<<dim3(DD*EE/256, 8), blk, 0, stream>>>(gb);
    TS8 gc;
    for(int h=0;h<HH;h++){
      gc.t[h]   = {p.ig_w + (size_t)h*HDIM*HDIM, w.igt_h + (size_t)h*HDIM*HDIM,
                   w.igt_l + (size_t)h*HDIM*HDIM, HDIM, HDIM};
      gc.t[4+h] = {p.ag_w + (size_t)h*HDIM*HDIM, w.agt_h + (size_t)h*HDIM*HDIM,
                   w.agt_l + (size_t)h*HDIM*HDIM, HDIM, HDIM};
    }
    tsplit8_k<<<dim3(HDIM*HDIM/256, 8), blk, 0, stream>>>(gc);
  }

  // ---- prologue ----
  ln_z_k<<<RR/4, blk, 0, stream>>>(skip, p.ln_gamma, p.ln_beta, NPh, NPl, Z);
  gemm_mfma<128,1,0,1,3><<<g2,blk,0,stream>>>(NPh,NPl, w.proj_h,w.proj_l, USN,USN,
      p.proj_b,nullptr,nullptr, nullptr, X0h, X0l, DD,DD,DD);
  gemm_mfma<128,1,0,0,3><<<g2,blk,0,stream>>>(X0h,X0l, w.fconv_h,w.fconv_l, USN,USN,
      p.fconv_b,nullptr,nullptr, XB2, USN,USN, DD,DD,DD);
  gemm_mfma<128,1,0,0,3><<<g2,blk,0,stream>>>(X0h,X0l, w.bconv_h,w.bconv_l, USN,USN,
      p.bconv_b,nullptr,nullptr, XB2 + RD, USN,USN, DD,DD,DD);

  // ---- residual block 0: recurrent (merged, M=32768) ----
  rms_h_k<<<RR2/4, blk, 0, stream>>>(XB2, p.rn0_t, NPh);
  gemm_mfma<128,3,0,5,2><<<g2m,blk,0,stream>>>(NPh,USN, w.ly_h,w.ly_l, USN,USN,
      p.ly_b,nullptr,nullptr, nullptr, Yh, USN, DD,DD,DD);
  gemm_mfma<128,1,0,0,2><<<g2m,blk,0,stream>>>(NPh,USN, w.lx_h,w.lx_l, USN,USN,
      p.lx_b,nullptr,nullptr, XR2, USN,USN, DD,DD,DD);
  gates_conv_k<<<ggm,blk,0,stream>>>(XR2, p.c1d_w, p.c1d_b,
      w.igt_h, w.igt_l, w.agt_h, w.agt_l, p.ig_b, p.ag_b, p.a_param, Abuf, BT);
  scan1_k<<<8*NCH*DD/256, blk,0,stream>>>(Abuf, BT, CSA, CSB);
  scan2_k<<<8*DD/256, blk,0,stream>>>(CSA, CSB);
  scan3_k<<<8*NCH*DD/256, blk,0,stream>>>(Abuf, BT, CSB, Yh, HYh);
  gemm_mfma<128,9,0,0,2><<<g2m,blk,0,stream>>>(HYh,USN, w.lo_h,w.lo_l, USN,USN,
      p.lo_b,nullptr, XB2, CV2, USN,USN, DD,DD,DD);
  rms_h_k<<<RR2/4,blk,0,stream>>>(CV2, p.rn0_c, NPh);
  gemm_mfma<64,1,1,5,1><<<gdual,blk,0,stream>>>(NPh,USN, w.up0a_h,USN,
      w.up0b_h,USN, p.mlp0_up_b, p.mlp0_up_b+EE, nullptr, nullptr,
      ACTh, USN, DD,DD,EE);
  gemm_mfma<128,9,0,0,2><<<g2m,blk,0,stream>>>(ACTh,USN, w.dn0_h,w.dn0_l, USN,USN,
      p.mlp0_dn_b,nullptr, CV2, XB2, USN,USN, EE,EE,DD);

  // ---- residual block 1: local attention (merged) ----
  rms_k<<<RR2/4,blk,0,stream>>>(XB2, p.rn1_t, NPh, NPl);
  gemm_mfma<128,0,0,2,2><<<g2m,blk,0,stream>>>(NPh,USN, w.q_h,w.q_l, USN,USN,
      nullptr,nullptr,nullptr, nullptr, Qph, Qpl, DD,DD,DD);
  gemm_mfma<64,0,1,7,3><<<g64m,blk,0,stream>>>(NPh,NPl, w.k_h,w.k_l, w.v_h,w.v_l,
      nullptr,nullptr,nullptr, (float*)Vt, KPh, KPl, DD,DD,HDIM);
  attn_k<<<dim3(64,4,8),blk,0,stream>>>(Qph, Qpl, KPh, KPl, Vt, P2h, P2l);
  gemm_mfma<128,9,0,0,2><<<g2m,blk,0,stream>>>(P2h,USN, w.o_h,w.o_l, USN,USN,
      p.o_b,nullptr, XB2, CV2, USN,USN, DD,DD,DD);
  rms_h_k<<<RR2/4,blk,0,stream>>>(CV2, p.rn1_c, NPh);
  gemm_mfma<64,1,1,5,1><<<gdual,blk,0,stream>>>(NPh,USN, w.up1a_h,USN,
      w.up1b_h,USN, p.mlp1_up_b, p.mlp1_up_b+EE, nullptr, nullptr,
      ACTh, USN, DD,DD,EE);
  gemm_mfma<128,9,0,0,2><<<g2m,blk,0,stream>>>(ACTh,USN, w.dn1_h,w.dn1_l, USN,USN,
      p.mlp1_dn_b,nullptr, CV2, XB2, USN,USN, EE,EE,DD);

  // ---- combine ----
  comb_k<<<RR*DD/256, blk, 0, stream>>>(OUT2, OUT2 + RD, Z, skip, (float*)d_out);
}